// Round 2
// baseline (1610.000 us; speedup 1.0000x reference)
//
#include <hip/hip_runtime.h>
#include <hip/hip_bf16.h>

// DKVMN forward. B=256 S=512 M=128 DK=128 DV=256 FC=128.
// Chunked over time so workspace fits ws_size:
//   per chunk: k1 (w=softmax(qe@MK^T)), k2 (e|a), k3 (sequential read/update,
//   mem in VGPRs, state buffer at chunk boundary), k4 (final MLP).

#define BB    256
#define SS    512
#define MM    128
#define DKk   128
#define DVv   256
#define FCc   128

// ---------------------------------------------------------------- transpose MK
__global__ __launch_bounds__(256) void kt_transpose(const float* __restrict__ mk,
                                                    float* __restrict__ mkt) {
    int idx = blockIdx.x * 256 + threadIdx.x;   // 64 blocks * 256 = 16384
    int m = idx >> 7, k = idx & 127;
    mkt[(size_t)k * MM + m] = mk[(size_t)m * DKk + k];
}

// ---------------------------------------------------------------- k1: w = softmax(qe @ MK^T)
// tile 64 rows x 128 cols (all M), micro 4x8, K=128. A in LDS, B=MKT streamed.
// Rows are chunk-local: r -> (b = r>>tcs, t = coff + (r&tcm)).
__global__ __launch_bounds__(256) void k1_scores(const int* __restrict__ q_data,
                                                 const float* __restrict__ q_tab,
                                                 const float* __restrict__ mkt,
                                                 float* __restrict__ w_buf,
                                                 int tcs, int tcm, int coff) {
    __shared__ float A[64][132];
    __shared__ int qidx[64];
    int t = threadIdx.x;
    int row0 = blockIdx.x * 64;
    if (t < 64) {
        int rl = row0 + t;
        qidx[t] = q_data[(rl >> tcs) * SS + coff + (rl & tcm)];
    }
    __syncthreads();
    #pragma unroll
    for (int i = 0; i < 8; ++i) {
        int f = t + 256 * i;
        int r = f >> 5, c4 = f & 31;
        float4 v = *reinterpret_cast<const float4*>(q_tab + (size_t)qidx[r] * DKk + c4 * 4);
        *reinterpret_cast<float4*>(&A[r][c4 * 4]) = v;
    }
    __syncthreads();
    int rg = t >> 4, cg = t & 15;     // rows rg*4.., cols cg*8..
    float acc[4][8];
    #pragma unroll
    for (int i = 0; i < 4; ++i)
        #pragma unroll
        for (int j = 0; j < 8; ++j) acc[i][j] = 0.f;

    for (int k = 0; k < 128; k += 4) {
        float a_[4][4];
        #pragma unroll
        for (int i = 0; i < 4; ++i) {
            float4 v = *reinterpret_cast<const float4*>(&A[rg * 4 + i][k]);
            a_[i][0] = v.x; a_[i][1] = v.y; a_[i][2] = v.z; a_[i][3] = v.w;
        }
        #pragma unroll
        for (int kk = 0; kk < 4; ++kk) {
            const float* bp = mkt + (size_t)(k + kk) * MM + cg * 8;
            float4 b0 = *reinterpret_cast<const float4*>(bp);
            float4 b1 = *reinterpret_cast<const float4*>(bp + 4);
            #pragma unroll
            for (int i = 0; i < 4; ++i) {
                float av = a_[i][kk];
                acc[i][0] = fmaf(av, b0.x, acc[i][0]);
                acc[i][1] = fmaf(av, b0.y, acc[i][1]);
                acc[i][2] = fmaf(av, b0.z, acc[i][2]);
                acc[i][3] = fmaf(av, b0.w, acc[i][3]);
                acc[i][4] = fmaf(av, b1.x, acc[i][4]);
                acc[i][5] = fmaf(av, b1.y, acc[i][5]);
                acc[i][6] = fmaf(av, b1.z, acc[i][6]);
                acc[i][7] = fmaf(av, b1.w, acc[i][7]);
            }
        }
    }
    // softmax per row: 128 cols over 16 lanes (lane bits 0-3)
    #pragma unroll
    for (int i = 0; i < 4; ++i) {
        float mx = acc[i][0];
        #pragma unroll
        for (int j = 1; j < 8; ++j) mx = fmaxf(mx, acc[i][j]);
        for (int off = 1; off < 16; off <<= 1) mx = fmaxf(mx, __shfl_xor(mx, off, 64));
        float s = 0.f;
        #pragma unroll
        for (int j = 0; j < 8; ++j) { float p = expf(acc[i][j] - mx); acc[i][j] = p; s += p; }
        for (int off = 1; off < 16; off <<= 1) s += __shfl_xor(s, off, 64);
        float inv = 1.f / s;
        #pragma unroll
        for (int j = 0; j < 8; ++j) acc[i][j] *= inv;
        size_t ro = (size_t)(row0 + rg * 4 + i) * MM + cg * 8;
        *reinterpret_cast<float4*>(w_buf + ro)     = make_float4(acc[i][0], acc[i][1], acc[i][2], acc[i][3]);
        *reinterpret_cast<float4*>(w_buf + ro + 4) = make_float4(acc[i][4], acc[i][5], acc[i][6], acc[i][7]);
    }
}

// ---------------------------------------------------------------- k2: e|a = act(qae @ [We|Wa]^T)
// grid = (rows/32) * 4 col-blocks of 128. tile 32x128, micro 4x4, K=256.
__global__ __launch_bounds__(256) void k2_ea(const int* __restrict__ qa_data,
                                             const float* __restrict__ qa_tab,
                                             const float* __restrict__ W_er,
                                             const float* __restrict__ b_er,
                                             const float* __restrict__ W_ad,
                                             const float* __restrict__ b_ad,
                                             float* __restrict__ ea_buf,
                                             int tcs, int tcm, int coff) {
    __shared__ float A[32][260];
    __shared__ float BT[32][132];
    __shared__ int qidx[32];
    int t = threadIdx.x;
    int rb = blockIdx.x >> 2;
    int cb = blockIdx.x & 3;
    int row0 = rb * 32;
    int col0 = cb * 128;
    if (t < 32) {
        int rl = row0 + t;
        qidx[t] = qa_data[(rl >> tcs) * SS + coff + (rl & tcm)];
    }
    __syncthreads();
    #pragma unroll
    for (int i = 0; i < 8; ++i) {
        int f = t + 256 * i;
        int r = f >> 6, c4 = f & 63;
        float4 v = *reinterpret_cast<const float4*>(qa_tab + (size_t)qidx[r] * DVv + c4 * 4);
        *reinterpret_cast<float4*>(&A[r][c4 * 4]) = v;
    }
    int rg = t >> 5, cg = t & 31;  // rows rg*4.., cols cg*4..
    float acc[4][4];
    #pragma unroll
    for (int i = 0; i < 4; ++i)
        #pragma unroll
        for (int j = 0; j < 4; ++j) acc[i][j] = 0.f;

    const float* Wsrc = (col0 < 256) ? W_er : W_ad;
    int wcol0 = col0 & 255;
    for (int ks = 0; ks < 256; ks += 32) {
        __syncthreads();
        #pragma unroll
        for (int i = 0; i < 4; ++i) {
            int f = t + 256 * i;
            int c = f >> 3, k4 = f & 7;
            float4 v = *reinterpret_cast<const float4*>(Wsrc + (size_t)(wcol0 + c) * DVv + ks + k4 * 4);
            BT[k4 * 4 + 0][c] = v.x;
            BT[k4 * 4 + 1][c] = v.y;
            BT[k4 * 4 + 2][c] = v.z;
            BT[k4 * 4 + 3][c] = v.w;
        }
        __syncthreads();
        for (int k = 0; k < 32; k += 4) {
            float a_[4][4];
            #pragma unroll
            for (int i = 0; i < 4; ++i) {
                float4 v = *reinterpret_cast<const float4*>(&A[rg * 4 + i][ks + k]);
                a_[i][0] = v.x; a_[i][1] = v.y; a_[i][2] = v.z; a_[i][3] = v.w;
            }
            #pragma unroll
            for (int kk = 0; kk < 4; ++kk) {
                float4 b = *reinterpret_cast<const float4*>(&BT[k + kk][cg * 4]);
                #pragma unroll
                for (int i = 0; i < 4; ++i) {
                    float av = a_[i][kk];
                    acc[i][0] = fmaf(av, b.x, acc[i][0]);
                    acc[i][1] = fmaf(av, b.y, acc[i][1]);
                    acc[i][2] = fmaf(av, b.z, acc[i][2]);
                    acc[i][3] = fmaf(av, b.w, acc[i][3]);
                }
            }
        }
    }
    const float* bias = (col0 < 256) ? b_er : b_ad;
    bool is_e = (col0 < 256);
    #pragma unroll
    for (int i = 0; i < 4; ++i) {
        #pragma unroll
        for (int j = 0; j < 4; ++j) {
            int c = wcol0 + cg * 4 + j;
            float x = acc[i][j] + bias[c];
            acc[i][j] = is_e ? (1.f / (1.f + expf(-x))) : tanhf(x);
        }
        *reinterpret_cast<float4*>(ea_buf + (size_t)(row0 + rg * 4 + i) * 512 + col0 + cg * 4) =
            make_float4(acc[i][0], acc[i][1], acc[i][2], acc[i][3]);
    }
}

// ---------------------------------------------------------------- k3: sequential read/update
// one block (256 thr = 4 waves) per batch; lane owns one d; mem[128] in VGPRs.
__global__ __launch_bounds__(256, 1) void k3_seq(const float* __restrict__ w_buf,
                                                 const float* __restrict__ ea_buf,
                                                 const float* __restrict__ init_mem,
                                                 float* __restrict__ state,
                                                 float* __restrict__ reads_buf,
                                                 int TC, int first, int last) {
    int b = blockIdx.x;
    int wv = threadIdx.x >> 6, lane = threadIdx.x & 63;
    int d = wv * 64 + lane;
    float mem[128];
    if (first) {
        #pragma unroll
        for (int m = 0; m < 128; ++m) mem[m] = init_mem[(size_t)m * DVv + d];
    } else {
        #pragma unroll
        for (int m = 0; m < 128; ++m) mem[m] = state[((size_t)(b * 128 + m)) * DVv + d];
    }
    size_t rb = (size_t)b * TC;
    float2 w2 = *reinterpret_cast<const float2*>(w_buf + rb * MM + 2 * lane);
    float ev = ea_buf[rb * 512 + d];
    float av = ea_buf[rb * 512 + 256 + d];
    for (int t = 0; t < TC; ++t) {
        int tn = (t + 1 < TC) ? (t + 1) : t;
        size_t rn = rb + tn;
        float2 w2n = *reinterpret_cast<const float2*>(w_buf + rn * MM + 2 * lane);
        float evn = ea_buf[rn * 512 + d];
        float avn = ea_buf[rn * 512 + 256 + d];
        float rd0 = 0.f, rd1 = 0.f;
        #pragma unroll
        for (int m = 0; m < 128; m += 2) {
            float wa = __int_as_float(__builtin_amdgcn_readlane(__float_as_int(w2.x), m >> 1));
            float wb = __int_as_float(__builtin_amdgcn_readlane(__float_as_int(w2.y), m >> 1));
            rd0 = fmaf(wa, mem[m], rd0);
            mem[m] = fmaf(-(wa * ev), mem[m], mem[m]);
            mem[m] = fmaf(wa, av, mem[m]);
            rd1 = fmaf(wb, mem[m + 1], rd1);
            mem[m + 1] = fmaf(-(wb * ev), mem[m + 1], mem[m + 1]);
            mem[m + 1] = fmaf(wb, av, mem[m + 1]);
        }
        reads_buf[(rb + t) * DVv + d] = rd0 + rd1;
        w2 = w2n; ev = evn; av = avn;
    }
    if (!last) {
        #pragma unroll
        for (int m = 0; m < 128; ++m) state[((size_t)(b * 128 + m)) * DVv + d] = mem[m];
    }
}

// ---------------------------------------------------------------- k4: logits
// tile 32 rows x 128 cols, micro 4x4, K=384.
__global__ __launch_bounds__(256) void k4_final(const int* __restrict__ q_data,
                                                const float* __restrict__ q_tab,
                                                const float* __restrict__ reads_buf,
                                                const float* __restrict__ W_rd,
                                                const float* __restrict__ b_rd,
                                                const float* __restrict__ W_pr,
                                                const float* __restrict__ b_pr,
                                                float* __restrict__ out,
                                                int tcs, int tcm, int coff) {
    __shared__ float A[32][36];
    __shared__ float BT[32][132];
    __shared__ int qidx[32];
    int t = threadIdx.x;
    int row0 = blockIdx.x * 32;
    if (t < 32) {
        int rl = row0 + t;
        qidx[t] = q_data[(rl >> tcs) * SS + coff + (rl & tcm)];
    }
    int rg = t >> 5, cg = t & 31;
    float acc[4][4];
    #pragma unroll
    for (int i = 0; i < 4; ++i)
        #pragma unroll
        for (int j = 0; j < 4; ++j) acc[i][j] = 0.f;

    for (int ks = 0; ks < 384; ks += 32) {
        __syncthreads();
        {
            int r = t >> 3, k4 = t & 7;
            int kg = ks + k4 * 4;
            float4 v;
            if (kg < 256)
                v = *reinterpret_cast<const float4*>(reads_buf + (size_t)(row0 + r) * DVv + kg);
            else
                v = *reinterpret_cast<const float4*>(q_tab + (size_t)qidx[r] * DKk + (kg - 256));
            *reinterpret_cast<float4*>(&A[r][k4 * 4]) = v;
        }
        #pragma unroll
        for (int i = 0; i < 4; ++i) {
            int f = t + 256 * i;
            int c = f >> 3, k4 = f & 7;
            float4 v = *reinterpret_cast<const float4*>(W_rd + (size_t)c * 384 + ks + k4 * 4);
            BT[k4 * 4 + 0][c] = v.x;
            BT[k4 * 4 + 1][c] = v.y;
            BT[k4 * 4 + 2][c] = v.z;
            BT[k4 * 4 + 3][c] = v.w;
        }
        __syncthreads();
        for (int k = 0; k < 32; k += 4) {
            float a_[4][4];
            #pragma unroll
            for (int i = 0; i < 4; ++i) {
                float4 v = *reinterpret_cast<const float4*>(&A[rg * 4 + i][k]);
                a_[i][0] = v.x; a_[i][1] = v.y; a_[i][2] = v.z; a_[i][3] = v.w;
            }
            #pragma unroll
            for (int kk = 0; kk < 4; ++kk) {
                float4 b = *reinterpret_cast<const float4*>(&BT[k + kk][cg * 4]);
                #pragma unroll
                for (int i = 0; i < 4; ++i) {
                    float av = a_[i][kk];
                    acc[i][0] = fmaf(av, b.x, acc[i][0]);
                    acc[i][1] = fmaf(av, b.y, acc[i][1]);
                    acc[i][2] = fmaf(av, b.z, acc[i][2]);
                    acc[i][3] = fmaf(av, b.w, acc[i][3]);
                }
            }
        }
    }
    float h[4][4];
    #pragma unroll
    for (int i = 0; i < 4; ++i)
        #pragma unroll
        for (int j = 0; j < 4; ++j)
            h[i][j] = tanhf(acc[i][j] + b_rd[cg * 4 + j]);
    __syncthreads();
    #pragma unroll
    for (int i = 0; i < 4; ++i)
        *reinterpret_cast<float4*>(&BT[rg * 4 + i][cg * 4]) =
            make_float4(h[i][0], h[i][1], h[i][2], h[i][3]);
    __syncthreads();
    int wv = t >> 6, lane = t & 63;
    float2 wp = *reinterpret_cast<const float2*>(W_pr + 2 * lane);
    float bp = b_pr[0];
    for (int rr = 0; rr < 8; ++rr) {
        int r = wv * 8 + rr;
        float2 h2 = *reinterpret_cast<const float2*>(&BT[r][2 * lane]);
        float s = h2.x * wp.x + h2.y * wp.y;
        for (int off = 1; off < 64; off <<= 1) s += __shfl_xor(s, off, 64);
        if (lane == 0) {
            int rl = row0 + r;
            out[(rl >> tcs) * SS + coff + (rl & tcm)] = s + bp;
        }
    }
}

// ---------------------------------------------------------------- launch
extern "C" void kernel_launch(void* const* d_in, const int* in_sizes, int n_in,
                              void* d_out, int out_size, void* d_ws, size_t ws_size,
                              hipStream_t stream) {
    const int*   q_data   = (const int*)d_in[0];
    const int*   qa_data  = (const int*)d_in[1];
    const float* q_tab    = (const float*)d_in[2];
    const float* qa_tab   = (const float*)d_in[3];
    const float* mk       = (const float*)d_in[4];
    const float* init_mem = (const float*)d_in[5];
    const float* W_er     = (const float*)d_in[6];
    const float* b_er     = (const float*)d_in[7];
    const float* W_ad     = (const float*)d_in[8];
    const float* b_ad     = (const float*)d_in[9];
    const float* W_rd     = (const float*)d_in[10];
    const float* b_rd     = (const float*)d_in[11];
    const float* W_pr     = (const float*)d_in[12];
    const float* b_pr     = (const float*)d_in[13];
    float* out = (float*)d_out;

    // pick largest chunk TC (power of 2) whose buffers fit ws_size
    size_t avail_f = ws_size / 4;
    const size_t state_f = (size_t)BB * MM * DVv;   // 8,388,608
    int TC = 8;
    {
        const int cand[] = {512, 256, 128, 64, 32, 16, 8};
        for (int i = 0; i < 7; ++i) {
            size_t need = 16384 + state_f + (size_t)BB * cand[i] * (MM + 512 + DVv);
            if (need <= avail_f) { TC = cand[i]; break; }
        }
    }
    int NC = SS / TC;
    int tcs = __builtin_ctz(TC);
    int tcm = TC - 1;

    float* ws      = (float*)d_ws;
    float* mkt     = ws;                                    // 16384
    float* state   = mkt + 16384;                           // 8,388,608
    float* w_buf   = state + state_f;                       // B*TC*128
    float* ea_buf  = w_buf + (size_t)BB * TC * MM;          // B*TC*512
    float* reads   = ea_buf + (size_t)BB * TC * 512;        // B*TC*256

    kt_transpose<<<64, 256, 0, stream>>>(mk, mkt);
    for (int c = 0; c < NC; ++c) {
        int coff = c * TC;
        int rows = BB * TC;
        k1_scores<<<rows / 64, 256, 0, stream>>>(q_data, q_tab, mkt, w_buf, tcs, tcm, coff);
        k2_ea<<<(rows / 32) * 4, 256, 0, stream>>>(qa_data, qa_tab, W_er, b_er, W_ad, b_ad,
                                                   ea_buf, tcs, tcm, coff);
        k3_seq<<<BB, 256, 0, stream>>>(w_buf, ea_buf, init_mem, state, reads,
                                       TC, c == 0, c == NC - 1);
        k4_final<<<rows / 32, 256, 0, stream>>>(q_data, q_tab, reads, W_rd, b_rd, W_pr, b_pr,
                                                out, tcs, tcm, coff);
    }
}

// Round 3
// 983.835 us; speedup vs baseline: 1.6365x; 1.6365x over previous
//
#include <hip/hip_runtime.h>
#include <hip/hip_bf16.h>

// DKVMN forward. B=256 S=512 M=128 DK=128 DV=256 FC=128.
// Chunked over time (TC chosen to fit ws_size). Per chunk:
//   k1 (fp32): w = softmax(qe @ MK^T)
//   k2 (bf16 MFMA): e|a = act(qa @ [We|Wa]^T)
//   k3: sequential read/update, mem in VGPRs (packed f32x2, v_pk_fma), 16 waves/batch
//   k4 (fp32): logits = Wp @ tanh(Wr @ [read|qe])

#define BB    256
#define SS    512
#define MM    128
#define DKk   128
#define DVv   256

typedef float  f32x2  __attribute__((ext_vector_type(2)));
typedef float  f32x4  __attribute__((ext_vector_type(4)));
typedef short  bf16x8 __attribute__((ext_vector_type(8)));

static __device__ __forceinline__ unsigned short f2bf(float f) {
    unsigned u = __float_as_uint(f);
    unsigned r = (u + 0x7FFFu + ((u >> 16) & 1u)) >> 16;
    return (unsigned short)r;
}

// ---------------------------------------------------------------- transpose MK (fp32, for k1)
__global__ __launch_bounds__(256) void kt_transpose(const float* __restrict__ mk,
                                                    float* __restrict__ mkt) {
    int idx = blockIdx.x * 256 + threadIdx.x;   // 64 blocks
    int m = idx >> 7, k = idx & 127;
    mkt[(size_t)k * MM + m] = mk[(size_t)m * DKk + k];
}

// ---------------------------------------------------------------- convert tables to bf16
__global__ __launch_bounds__(256) void kcvt(const float* __restrict__ qa_tab,
                                            const float* __restrict__ W_er,
                                            const float* __restrict__ W_ad,
                                            unsigned short* __restrict__ qa16,
                                            unsigned short* __restrict__ wea16) {
    const int n_qa = 20001 * 256;
    for (int i = blockIdx.x * 256 + threadIdx.x; i < n_qa; i += gridDim.x * 256)
        qa16[i] = f2bf(qa_tab[i]);
    for (int i = blockIdx.x * 256 + threadIdx.x; i < 65536; i += gridDim.x * 256) {
        wea16[i] = f2bf(W_er[i]);
        wea16[65536 + i] = f2bf(W_ad[i]);
    }
}

// ---------------------------------------------------------------- k1: w = softmax(qe @ MK^T)  (fp32)
__global__ __launch_bounds__(256) void k1_scores(const int* __restrict__ q_data,
                                                 const float* __restrict__ q_tab,
                                                 const float* __restrict__ mkt,
                                                 float* __restrict__ w_buf,
                                                 int tcs, int tcm, int coff) {
    __shared__ float A[64][132];
    __shared__ int qidx[64];
    int t = threadIdx.x;
    int row0 = blockIdx.x * 64;
    if (t < 64) {
        int rl = row0 + t;
        qidx[t] = q_data[(rl >> tcs) * SS + coff + (rl & tcm)];
    }
    __syncthreads();
    #pragma unroll
    for (int i = 0; i < 8; ++i) {
        int f = t + 256 * i;
        int r = f >> 5, c4 = f & 31;
        float4 v = *reinterpret_cast<const float4*>(q_tab + (size_t)qidx[r] * DKk + c4 * 4);
        *reinterpret_cast<float4*>(&A[r][c4 * 4]) = v;
    }
    __syncthreads();
    int rg = t >> 4, cg = t & 15;
    float acc[4][8];
    #pragma unroll
    for (int i = 0; i < 4; ++i)
        #pragma unroll
        for (int j = 0; j < 8; ++j) acc[i][j] = 0.f;

    for (int k = 0; k < 128; k += 4) {
        float a_[4][4];
        #pragma unroll
        for (int i = 0; i < 4; ++i) {
            float4 v = *reinterpret_cast<const float4*>(&A[rg * 4 + i][k]);
            a_[i][0] = v.x; a_[i][1] = v.y; a_[i][2] = v.z; a_[i][3] = v.w;
        }
        #pragma unroll
        for (int kk = 0; kk < 4; ++kk) {
            const float* bp = mkt + (size_t)(k + kk) * MM + cg * 8;
            float4 b0 = *reinterpret_cast<const float4*>(bp);
            float4 b1 = *reinterpret_cast<const float4*>(bp + 4);
            #pragma unroll
            for (int i = 0; i < 4; ++i) {
                float av = a_[i][kk];
                acc[i][0] = fmaf(av, b0.x, acc[i][0]);
                acc[i][1] = fmaf(av, b0.y, acc[i][1]);
                acc[i][2] = fmaf(av, b0.z, acc[i][2]);
                acc[i][3] = fmaf(av, b0.w, acc[i][3]);
                acc[i][4] = fmaf(av, b1.x, acc[i][4]);
                acc[i][5] = fmaf(av, b1.y, acc[i][5]);
                acc[i][6] = fmaf(av, b1.z, acc[i][6]);
                acc[i][7] = fmaf(av, b1.w, acc[i][7]);
            }
        }
    }
    #pragma unroll
    for (int i = 0; i < 4; ++i) {
        float mx = acc[i][0];
        #pragma unroll
        for (int j = 1; j < 8; ++j) mx = fmaxf(mx, acc[i][j]);
        for (int off = 1; off < 16; off <<= 1) mx = fmaxf(mx, __shfl_xor(mx, off, 64));
        float s = 0.f;
        #pragma unroll
        for (int j = 0; j < 8; ++j) { float p = expf(acc[i][j] - mx); acc[i][j] = p; s += p; }
        for (int off = 1; off < 16; off <<= 1) s += __shfl_xor(s, off, 64);
        float inv = 1.f / s;
        #pragma unroll
        for (int j = 0; j < 8; ++j) acc[i][j] *= inv;
        size_t ro = (size_t)(row0 + rg * 4 + i) * MM + cg * 8;
        *reinterpret_cast<float4*>(w_buf + ro)     = make_float4(acc[i][0], acc[i][1], acc[i][2], acc[i][3]);
        *reinterpret_cast<float4*>(w_buf + ro + 4) = make_float4(acc[i][4], acc[i][5], acc[i][6], acc[i][7]);
    }
}

// ---------------------------------------------------------------- k2: e|a via bf16 MFMA
// grid = (rows/128) * 4 colblocks; block 256 thr = 4 waves (2x2), wave = 64x64 out.
__global__ __launch_bounds__(256) void k2_ea_mfma(const int* __restrict__ qa_data,
                                                  const unsigned short* __restrict__ qa16,
                                                  const unsigned short* __restrict__ wea16,
                                                  const float* __restrict__ b_er,
                                                  const float* __restrict__ b_ad,
                                                  float* __restrict__ ea_buf,
                                                  int tcs, int tcm, int coff) {
    __shared__ __align__(16) unsigned short A_lds[128 * 64];
    __shared__ int qidx[128];
    int t = threadIdx.x;
    int rb = blockIdx.x >> 2, cb = blockIdx.x & 3;
    int row0 = rb * 128;
    if (t < 128) {
        int rl = row0 + t;
        qidx[t] = qa_data[(rl >> tcs) * SS + coff + (rl & tcm)];
    }
    int l = t & 63;
    int wid = t >> 6, wr = wid >> 1, wc = wid & 1;
    f32x4 acc[4][4];
    #pragma unroll
    for (int i = 0; i < 4; ++i)
        #pragma unroll
        for (int j = 0; j < 4; ++j)
            acc[i][j] = (f32x4){0.f, 0.f, 0.f, 0.f};

    for (int ks = 0; ks < 256; ks += 64) {
        __syncthreads();
        // stage A tile: 128 rows x 64 k, layout [r][kb_phys] 16B units, kb_phys = kb_log ^ (r&7)
        #pragma unroll
        for (int p = 0; p < 4; ++p) {
            int U = p * 256 + t;
            int r = U >> 3, kb = U & 7;
            int kb_log = kb ^ (r & 7);
            int4 v = *reinterpret_cast<const int4*>(qa16 + (size_t)qidx[r] * 256 + ks + kb_log * 8);
            *reinterpret_cast<int4*>(&A_lds[U * 8]) = v;
        }
        __syncthreads();
        #pragma unroll
        for (int ksub = 0; ksub < 2; ++ksub) {
            bf16x8 af[4];
            #pragma unroll
            for (int mi = 0; mi < 4; ++mi) {
                int r = wr * 64 + mi * 16 + (l & 15);
                int kb_log = ksub * 4 + (l >> 4);
                int pu = r * 8 + (kb_log ^ (r & 7));
                af[mi] = *reinterpret_cast<const bf16x8*>(&A_lds[pu * 8]);
            }
            #pragma unroll
            for (int nj = 0; nj < 4; ++nj) {
                int col = cb * 128 + wc * 64 + nj * 16 + (l & 15);
                bf16x8 bf = *reinterpret_cast<const bf16x8*>(
                    wea16 + (size_t)col * 256 + ks + ksub * 32 + (l >> 4) * 8);
                #pragma unroll
                for (int mi = 0; mi < 4; ++mi)
                    acc[mi][nj] = __builtin_amdgcn_mfma_f32_16x16x32_bf16(af[mi], bf, acc[mi][nj], 0, 0, 0);
            }
        }
    }
    // epilogue: bias + sigmoid/tanh, store fp32
    #pragma unroll
    for (int nj = 0; nj < 4; ++nj) {
        int col = cb * 128 + wc * 64 + nj * 16 + (l & 15);
        bool is_e = (cb < 2);
        float bias = is_e ? b_er[col] : b_ad[col - 256];
        #pragma unroll
        for (int mi = 0; mi < 4; ++mi) {
            #pragma unroll
            for (int reg = 0; reg < 4; ++reg) {
                int rl = row0 + wr * 64 + mi * 16 + (l >> 4) * 4 + reg;
                float x = acc[mi][nj][reg] + bias;
                float y = is_e ? (1.f / (1.f + expf(-x))) : tanhf(x);
                ea_buf[(size_t)rl * 512 + col] = y;
            }
        }
    }
}

// ---------------------------------------------------------------- k3: sequential read/update
// 1 block (1024 thr = 16 waves) per batch. wave = (m-quarter mq, d-quarter dq).
// mem as 16 packed f32x2 over m-pairs; w broadcast via uniform ds_read_b64;
// partial reads combined via double-buffered LDS, 1 barrier/step.
__global__ __launch_bounds__(1024, 1) void k3_seq(const float* __restrict__ w_buf,
                                                  const float* __restrict__ ea_buf,
                                                  const float* __restrict__ init_mem,
                                                  float* __restrict__ state,
                                                  float* __restrict__ reads_buf,
                                                  int TC, int first, int last) {
    __shared__ float wlds[2][128];
    __shared__ float rdlds[2][4][256];
    int b = blockIdx.x;
    int tid = threadIdx.x;
    int wv = tid >> 6, lane = tid & 63;
    int mq = wv >> 2, dq = wv & 3;
    int d = dq * 64 + lane;
    int m0 = mq * 32;
    f32x2 mem[16];
    if (first) {
        #pragma unroll
        for (int i = 0; i < 16; ++i) {
            mem[i].x = init_mem[(size_t)(m0 + 2 * i) * DVv + d];
            mem[i].y = init_mem[(size_t)(m0 + 2 * i + 1) * DVv + d];
        }
    } else {
        #pragma unroll
        for (int i = 0; i < 16; ++i)
            mem[i] = *reinterpret_cast<const f32x2*>(&state[((size_t)b * DVv + d) * MM + m0 + 2 * i]);
    }
    size_t rb = (size_t)b * TC;
    if (wv == 15)
        *reinterpret_cast<float2*>(&wlds[0][lane * 2]) =
            *reinterpret_cast<const float2*>(&w_buf[rb * MM + lane * 2]);
    float e_c = ea_buf[rb * 512 + d];
    float a_c = ea_buf[rb * 512 + 256 + d];
    __syncthreads();
    for (int t = 0; t < TC; ++t) {
        int cur = t & 1, nxt = cur ^ 1;
        int tn = (t + 1 < TC) ? t + 1 : t;
        size_t rn = rb + tn;
        if (wv == 15)
            *reinterpret_cast<float2*>(&wlds[nxt][lane * 2]) =
                *reinterpret_cast<const float2*>(&w_buf[rn * MM + lane * 2]);
        float e_n = ea_buf[rn * 512 + d];
        float a_n = ea_buf[rn * 512 + 256 + d];
        f32x2 en2; en2.x = -e_c; en2.y = -e_c;
        f32x2 a2;  a2.x  = a_c;  a2.y  = a_c;
        f32x2 rd;  rd.x = 0.f;  rd.y = 0.f;
        const f32x2* wp = reinterpret_cast<const f32x2*>(&wlds[cur][m0]);
        #pragma unroll
        for (int i = 0; i < 16; ++i) {
            f32x2 w2 = wp[i];       // LDS broadcast (uniform address per wave)
            f32x2 tt;
            asm("v_pk_fma_f32 %0, %1, %2, %0" : "+v"(rd) : "v"(w2), "v"(mem[i]));      // rd += w*mem(old)
            asm("v_pk_mul_f32 %0, %1, %2"     : "=v"(tt) : "v"(w2), "v"(en2));         // tt = -w*e
            asm("v_pk_fma_f32 %0, %1, %0, %0" : "+v"(mem[i]) : "v"(tt));               // mem -= w*e*mem
            asm("v_pk_fma_f32 %0, %1, %2, %0" : "+v"(mem[i]) : "v"(w2), "v"(a2));      // mem += w*a
        }
        rdlds[cur][mq][d] = rd.x + rd.y;
        __syncthreads();
        if (mq == 0) {
            float s = rdlds[cur][0][d] + rdlds[cur][1][d] + rdlds[cur][2][d] + rdlds[cur][3][d];
            reads_buf[(rb + t) * DVv + d] = s;
        }
        e_c = e_n; a_c = a_n;
    }
    if (!last) {
        #pragma unroll
        for (int i = 0; i < 16; ++i)
            *reinterpret_cast<f32x2*>(&state[((size_t)b * DVv + d) * MM + m0 + 2 * i]) = mem[i];
    }
}

// ---------------------------------------------------------------- k4: logits (fp32)
__global__ __launch_bounds__(256) void k4_final(const int* __restrict__ q_data,
                                                const float* __restrict__ q_tab,
                                                const float* __restrict__ reads_buf,
                                                const float* __restrict__ W_rd,
                                                const float* __restrict__ b_rd,
                                                const float* __restrict__ W_pr,
                                                const float* __restrict__ b_pr,
                                                float* __restrict__ out,
                                                int tcs, int tcm, int coff) {
    __shared__ float A[32][36];
    __shared__ float BT[32][132];
    __shared__ int qidx[32];
    int t = threadIdx.x;
    int row0 = blockIdx.x * 32;
    if (t < 32) {
        int rl = row0 + t;
        qidx[t] = q_data[(rl >> tcs) * SS + coff + (rl & tcm)];
    }
    int rg = t >> 5, cg = t & 31;
    float acc[4][4];
    #pragma unroll
    for (int i = 0; i < 4; ++i)
        #pragma unroll
        for (int j = 0; j < 4; ++j) acc[i][j] = 0.f;

    for (int ks = 0; ks < 384; ks += 32) {
        __syncthreads();
        {
            int r = t >> 3, k4 = t & 7;
            int kg = ks + k4 * 4;
            float4 v;
            if (kg < 256)
                v = *reinterpret_cast<const float4*>(reads_buf + (size_t)(row0 + r) * DVv + kg);
            else
                v = *reinterpret_cast<const float4*>(q_tab + (size_t)qidx[r] * DKk + (kg - 256));
            *reinterpret_cast<float4*>(&A[r][k4 * 4]) = v;
        }
        #pragma unroll
        for (int i = 0; i < 4; ++i) {
            int f = t + 256 * i;
            int c = f >> 3, k4 = f & 7;
            float4 v = *reinterpret_cast<const float4*>(W_rd + (size_t)c * 384 + ks + k4 * 4);
            BT[k4 * 4 + 0][c] = v.x;
            BT[k4 * 4 + 1][c] = v.y;
            BT[k4 * 4 + 2][c] = v.z;
            BT[k4 * 4 + 3][c] = v.w;
        }
        __syncthreads();
        for (int k = 0; k < 32; k += 4) {
            float a_[4][4];
            #pragma unroll
            for (int i = 0; i < 4; ++i) {
                float4 v = *reinterpret_cast<const float4*>(&A[rg * 4 + i][k]);
                a_[i][0] = v.x; a_[i][1] = v.y; a_[i][2] = v.z; a_[i][3] = v.w;
            }
            #pragma unroll
            for (int kk = 0; kk < 4; ++kk) {
                float4 b = *reinterpret_cast<const float4*>(&BT[k + kk][cg * 4]);
                #pragma unroll
                for (int i = 0; i < 4; ++i) {
                    float av = a_[i][kk];
                    acc[i][0] = fmaf(av, b.x, acc[i][0]);
                    acc[i][1] = fmaf(av, b.y, acc[i][1]);
                    acc[i][2] = fmaf(av, b.z, acc[i][2]);
                    acc[i][3] = fmaf(av, b.w, acc[i][3]);
                }
            }
        }
    }
    float h[4][4];
    #pragma unroll
    for (int i = 0; i < 4; ++i)
        #pragma unroll
        for (int j = 0; j < 4; ++j)
            h[i][j] = tanhf(acc[i][j] + b_rd[cg * 4 + j]);
    __syncthreads();
    #pragma unroll
    for (int i = 0; i < 4; ++i)
        *reinterpret_cast<float4*>(&BT[rg * 4 + i][cg * 4]) =
            make_float4(h[i][0], h[i][1], h[i][2], h[i][3]);
    __syncthreads();
    int wv = t >> 6, lane = t & 63;
    float2 wp = *reinterpret_cast<const float2*>(W_pr + 2 * lane);
    float bp = b_pr[0];
    for (int rr = 0; rr < 8; ++rr) {
        int r = wv * 8 + rr;
        float2 h2 = *reinterpret_cast<const float2*>(&BT[r][2 * lane]);
        float s = h2.x * wp.x + h2.y * wp.y;
        for (int off = 1; off < 64; off <<= 1) s += __shfl_xor(s, off, 64);
        if (lane == 0) {
            int rl = row0 + r;
            out[(rl >> tcs) * SS + coff + (rl & tcm)] = s + bp;
        }
    }
}

// ---------------------------------------------------------------- launch
extern "C" void kernel_launch(void* const* d_in, const int* in_sizes, int n_in,
                              void* d_out, int out_size, void* d_ws, size_t ws_size,
                              hipStream_t stream) {
    const int*   q_data   = (const int*)d_in[0];
    const int*   qa_data  = (const int*)d_in[1];
    const float* q_tab    = (const float*)d_in[2];
    const float* qa_tab   = (const float*)d_in[3];
    const float* mk       = (const float*)d_in[4];
    const float* init_mem = (const float*)d_in[5];
    const float* W_er     = (const float*)d_in[6];
    const float* b_er     = (const float*)d_in[7];
    const float* W_ad     = (const float*)d_in[8];
    const float* b_ad     = (const float*)d_in[9];
    const float* W_rd     = (const float*)d_in[10];
    const float* b_rd     = (const float*)d_in[11];
    const float* W_pr     = (const float*)d_in[12];
    const float* b_pr     = (const float*)d_in[13];
    float* out = (float*)d_out;

    const size_t state_f = (size_t)BB * MM * DVv;          // 8,388,608 floats
    const size_t qa16_n  = (size_t)20001 * 256;            // ushorts
    const size_t wea16_n = 131072;                         // ushorts
    const size_t bf16_f  = (qa16_n + wea16_n + 1) / 2 + 8; // float-equivalents

    size_t avail_f = ws_size / 4;
    int TC = 8;
    {
        const int cand[] = {512, 256, 128, 64, 32, 16, 8};
        for (int i = 0; i < 7; ++i) {
            size_t need = 16384 + state_f + bf16_f + (size_t)BB * cand[i] * (MM + 512 + DVv);
            if (need <= avail_f) { TC = cand[i]; break; }
        }
    }
    int NC = SS / TC;
    int tcs = __builtin_ctz(TC);
    int tcm = TC - 1;

    float* ws      = (float*)d_ws;
    float* mkt     = ws;                                    // 16384
    float* state   = mkt + 16384;
    float* w_buf   = state + state_f;                       // B*TC*128
    float* ea_buf  = w_buf + (size_t)BB * TC * MM;          // B*TC*512
    float* reads   = ea_buf + (size_t)BB * TC * 512;        // B*TC*256
    unsigned short* qa16  = (unsigned short*)(reads + (size_t)BB * TC * DVv);
    unsigned short* wea16 = qa16 + qa16_n;

    kt_transpose<<<64, 256, 0, stream>>>(mk, mkt);
    kcvt<<<1024, 256, 0, stream>>>(qa_tab, W_er, W_ad, qa16, wea16);
    for (int c = 0; c < NC; ++c) {
        int coff = c * TC;
        int rows = BB * TC;
        k1_scores<<<rows / 64, 256, 0, stream>>>(q_data, q_tab, mkt, w_buf, tcs, tcm, coff);
        k2_ea_mfma<<<(rows / 128) * 4, 256, 0, stream>>>(qa_data, qa16, wea16, b_er, b_ad,
                                                         ea_buf, tcs, tcm, coff);
        k3_seq<<<BB, 1024, 0, stream>>>(w_buf, ea_buf, init_mem, state, reads,
                                        TC, c == 0, c == NC - 1);
        k4_final<<<rows / 32, 256, 0, stream>>>(q_data, q_tab, reads, W_rd, b_rd, W_pr, b_pr,
                                                out, tcs, tcm, coff);
    }
}

// Round 4
// 911.261 us; speedup vs baseline: 1.7668x; 1.0796x over previous
//
#include <hip/hip_runtime.h>
#include <hip/hip_bf16.h>

// DKVMN forward. B=256 S=512 M=128 DK=128 DV=256 FC=128.
// Chunked over time (TC chosen to fit ws_size). Per chunk:
//   k1 (fp32): w = softmax(qe @ MK^T)
//   k2 (bf16 MFMA): e|a = act(qa @ [We|Wa]^T)
//   k3: sequential read/update, mem in VGPRs (f32x2 pk ops, scalar-pipe w
//       broadcast, deferred read-combine every 8 steps)
//   k4 (fp32): logits = Wp @ tanh(Wr @ [read|qe])

#define BB    256
#define SS    512
#define MM    128
#define DKk   128
#define DVv   256

typedef float  f32x2  __attribute__((ext_vector_type(2)));
typedef float  f32x4  __attribute__((ext_vector_type(4)));
typedef short  bf16x8 __attribute__((ext_vector_type(8)));

static __device__ __forceinline__ unsigned short f2bf(float f) {
    unsigned u = __float_as_uint(f);
    unsigned r = (u + 0x7FFFu + ((u >> 16) & 1u)) >> 16;
    return (unsigned short)r;
}

// ---------------------------------------------------------------- transpose MK (fp32, for k1)
__global__ __launch_bounds__(256) void kt_transpose(const float* __restrict__ mk,
                                                    float* __restrict__ mkt) {
    int idx = blockIdx.x * 256 + threadIdx.x;   // 64 blocks
    int m = idx >> 7, k = idx & 127;
    mkt[(size_t)k * MM + m] = mk[(size_t)m * DKk + k];
}

// ---------------------------------------------------------------- convert tables to bf16
__global__ __launch_bounds__(256) void kcvt(const float* __restrict__ qa_tab,
                                            const float* __restrict__ W_er,
                                            const float* __restrict__ W_ad,
                                            unsigned short* __restrict__ qa16,
                                            unsigned short* __restrict__ wea16) {
    const int n_qa = 20001 * 256;
    for (int i = blockIdx.x * 256 + threadIdx.x; i < n_qa; i += gridDim.x * 256)
        qa16[i] = f2bf(qa_tab[i]);
    for (int i = blockIdx.x * 256 + threadIdx.x; i < 65536; i += gridDim.x * 256) {
        wea16[i] = f2bf(W_er[i]);
        wea16[65536 + i] = f2bf(W_ad[i]);
    }
}

// ---------------------------------------------------------------- k1: w = softmax(qe @ MK^T)  (fp32)
__global__ __launch_bounds__(256) void k1_scores(const int* __restrict__ q_data,
                                                 const float* __restrict__ q_tab,
                                                 const float* __restrict__ mkt,
                                                 float* __restrict__ w_buf,
                                                 int tcs, int tcm, int coff) {
    __shared__ float A[64][132];
    __shared__ int qidx[64];
    int t = threadIdx.x;
    int row0 = blockIdx.x * 64;
    if (t < 64) {
        int rl = row0 + t;
        qidx[t] = q_data[(rl >> tcs) * SS + coff + (rl & tcm)];
    }
    __syncthreads();
    #pragma unroll
    for (int i = 0; i < 8; ++i) {
        int f = t + 256 * i;
        int r = f >> 5, c4 = f & 31;
        float4 v = *reinterpret_cast<const float4*>(q_tab + (size_t)qidx[r] * DKk + c4 * 4);
        *reinterpret_cast<float4*>(&A[r][c4 * 4]) = v;
    }
    __syncthreads();
    int rg = t >> 4, cg = t & 15;
    float acc[4][8];
    #pragma unroll
    for (int i = 0; i < 4; ++i)
        #pragma unroll
        for (int j = 0; j < 8; ++j) acc[i][j] = 0.f;

    for (int k = 0; k < 128; k += 4) {
        float a_[4][4];
        #pragma unroll
        for (int i = 0; i < 4; ++i) {
            float4 v = *reinterpret_cast<const float4*>(&A[rg * 4 + i][k]);
            a_[i][0] = v.x; a_[i][1] = v.y; a_[i][2] = v.z; a_[i][3] = v.w;
        }
        #pragma unroll
        for (int kk = 0; kk < 4; ++kk) {
            const float* bp = mkt + (size_t)(k + kk) * MM + cg * 8;
            float4 b0 = *reinterpret_cast<const float4*>(bp);
            float4 b1 = *reinterpret_cast<const float4*>(bp + 4);
            #pragma unroll
            for (int i = 0; i < 4; ++i) {
                float av = a_[i][kk];
                acc[i][0] = fmaf(av, b0.x, acc[i][0]);
                acc[i][1] = fmaf(av, b0.y, acc[i][1]);
                acc[i][2] = fmaf(av, b0.z, acc[i][2]);
                acc[i][3] = fmaf(av, b0.w, acc[i][3]);
                acc[i][4] = fmaf(av, b1.x, acc[i][4]);
                acc[i][5] = fmaf(av, b1.y, acc[i][5]);
                acc[i][6] = fmaf(av, b1.z, acc[i][6]);
                acc[i][7] = fmaf(av, b1.w, acc[i][7]);
            }
        }
    }
    #pragma unroll
    for (int i = 0; i < 4; ++i) {
        float mx = acc[i][0];
        #pragma unroll
        for (int j = 1; j < 8; ++j) mx = fmaxf(mx, acc[i][j]);
        for (int off = 1; off < 16; off <<= 1) mx = fmaxf(mx, __shfl_xor(mx, off, 64));
        float s = 0.f;
        #pragma unroll
        for (int j = 0; j < 8; ++j) { float p = expf(acc[i][j] - mx); acc[i][j] = p; s += p; }
        for (int off = 1; off < 16; off <<= 1) s += __shfl_xor(s, off, 64);
        float inv = 1.f / s;
        #pragma unroll
        for (int j = 0; j < 8; ++j) acc[i][j] *= inv;
        size_t ro = (size_t)(row0 + rg * 4 + i) * MM + cg * 8;
        *reinterpret_cast<float4*>(w_buf + ro)     = make_float4(acc[i][0], acc[i][1], acc[i][2], acc[i][3]);
        *reinterpret_cast<float4*>(w_buf + ro + 4) = make_float4(acc[i][4], acc[i][5], acc[i][6], acc[i][7]);
    }
}

// ---------------------------------------------------------------- k2: e|a via bf16 MFMA
__global__ __launch_bounds__(256) void k2_ea_mfma(const int* __restrict__ qa_data,
                                                  const unsigned short* __restrict__ qa16,
                                                  const unsigned short* __restrict__ wea16,
                                                  const float* __restrict__ b_er,
                                                  const float* __restrict__ b_ad,
                                                  float* __restrict__ ea_buf,
                                                  int tcs, int tcm, int coff) {
    __shared__ __align__(16) unsigned short A_lds[128 * 64];
    __shared__ int qidx[128];
    int t = threadIdx.x;
    int rb = blockIdx.x >> 2, cb = blockIdx.x & 3;
    int row0 = rb * 128;
    if (t < 128) {
        int rl = row0 + t;
        qidx[t] = qa_data[(rl >> tcs) * SS + coff + (rl & tcm)];
    }
    int l = t & 63;
    int wid = t >> 6, wr = wid >> 1, wc = wid & 1;
    f32x4 acc[4][4];
    #pragma unroll
    for (int i = 0; i < 4; ++i)
        #pragma unroll
        for (int j = 0; j < 4; ++j)
            acc[i][j] = (f32x4){0.f, 0.f, 0.f, 0.f};

    for (int ks = 0; ks < 256; ks += 64) {
        __syncthreads();
        #pragma unroll
        for (int p = 0; p < 4; ++p) {
            int U = p * 256 + t;
            int r = U >> 3, kb = U & 7;
            int kb_log = kb ^ (r & 7);
            int4 v = *reinterpret_cast<const int4*>(qa16 + (size_t)qidx[r] * 256 + ks + kb_log * 8);
            *reinterpret_cast<int4*>(&A_lds[U * 8]) = v;
        }
        __syncthreads();
        #pragma unroll
        for (int ksub = 0; ksub < 2; ++ksub) {
            bf16x8 af[4];
            #pragma unroll
            for (int mi = 0; mi < 4; ++mi) {
                int r = wr * 64 + mi * 16 + (l & 15);
                int kb_log = ksub * 4 + (l >> 4);
                int pu = r * 8 + (kb_log ^ (r & 7));
                af[mi] = *reinterpret_cast<const bf16x8*>(&A_lds[pu * 8]);
            }
            #pragma unroll
            for (int nj = 0; nj < 4; ++nj) {
                int col = cb * 128 + wc * 64 + nj * 16 + (l & 15);
                bf16x8 bf = *reinterpret_cast<const bf16x8*>(
                    wea16 + (size_t)col * 256 + ks + ksub * 32 + (l >> 4) * 8);
                #pragma unroll
                for (int mi = 0; mi < 4; ++mi)
                    acc[mi][nj] = __builtin_amdgcn_mfma_f32_16x16x32_bf16(af[mi], bf, acc[mi][nj], 0, 0, 0);
            }
        }
    }
    #pragma unroll
    for (int nj = 0; nj < 4; ++nj) {
        int col = cb * 128 + wc * 64 + nj * 16 + (l & 15);
        bool is_e = (cb < 2);
        float bias = is_e ? b_er[col] : b_ad[col - 256];
        #pragma unroll
        for (int mi = 0; mi < 4; ++mi) {
            #pragma unroll
            for (int reg = 0; reg < 4; ++reg) {
                int rl = row0 + wr * 64 + mi * 16 + (l >> 4) * 4 + reg;
                float x = acc[mi][nj][reg] + bias;
                float y = is_e ? (1.f / (1.f + expf(-x))) : tanhf(x);
                ea_buf[(size_t)rl * 512 + col] = y;
            }
        }
    }
}

// ---------------------------------------------------------------- k3: sequential read/update
// 1 block (1024 thr = 16 waves) per batch; wave (mq,dq); mem 16x f32x2 over m-pairs.
// w broadcast via SCALAR loads (readfirstlane'd uniform pointer -> s_load),
// pk-fma with SGPR-pair operand. Read-combine deferred: G=8 steps per 2 barriers.
__global__ __launch_bounds__(1024, 1) void k3_seq(const float* __restrict__ w_buf,
                                                  const float* __restrict__ ea_buf,
                                                  const float* __restrict__ init_mem,
                                                  float* __restrict__ state,
                                                  float* __restrict__ reads_buf,
                                                  int TC, int first, int last) {
    __shared__ float rdlds[8][4][256];
    int b = blockIdx.x;
    int tid = threadIdx.x;
    int wv = tid >> 6, lane = tid & 63;
    int mq = wv >> 2, dq = wv & 3;
    int d = dq * 64 + lane;
    int m0 = mq * 32;
    f32x2 mem[16];
    if (first) {
        #pragma unroll
        for (int i = 0; i < 16; ++i) {
            mem[i].x = init_mem[(size_t)(m0 + 2 * i) * DVv + d];
            mem[i].y = init_mem[(size_t)(m0 + 2 * i + 1) * DVv + d];
        }
    } else {
        #pragma unroll
        for (int i = 0; i < 16; ++i)
            mem[i] = *reinterpret_cast<const f32x2*>(&state[((size_t)b * DVv + d) * MM + m0 + 2 * i]);
    }
    size_t rb = (size_t)b * TC;
    for (int t0 = 0; t0 < TC; t0 += 8) {
        // prefetch this batch's e/a (16 independent global loads, hides latency)
        float e8[8], a8[8];
        #pragma unroll
        for (int g = 0; g < 8; ++g) {
            size_t rr = (rb + t0 + g) * 512;
            e8[g] = ea_buf[rr + d];
            a8[g] = ea_buf[rr + 256 + d];
        }
        #pragma unroll
        for (int g = 0; g < 8; ++g) {
            // wave-uniform w row pointer -> scalar loads on the scalar pipe
            unsigned woff = (unsigned)((rb + t0 + g) * MM + m0);
            woff = (unsigned)__builtin_amdgcn_readfirstlane((int)woff);
            const f32x2* wp = reinterpret_cast<const f32x2*>(w_buf + woff);
            f32x2 rd; rd.x = 0.f; rd.y = 0.f;
            f32x2 ne2; ne2.x = -e8[g]; ne2.y = -e8[g];
            f32x2 a2;  a2.x = a8[g];  a2.y = a8[g];
            #pragma unroll
            for (int i = 0; i < 16; ++i) {
                f32x2 w2 = wp[i];
                f32x2 tt;
                asm("v_pk_fma_f32 %0, %1, %2, %0" : "+v"(rd)     : "s"(w2), "v"(mem[i]));   // rd += w*mem(old)
                asm("v_pk_fma_f32 %0, %1, %2, %3" : "=v"(tt)     : "v"(ne2), "v"(mem[i]), "v"(a2)); // tt = a - e*mem
                asm("v_pk_fma_f32 %0, %1, %2, %0" : "+v"(mem[i]) : "s"(w2), "v"(tt));       // mem += w*tt
            }
            rdlds[g][mq][d] = rd.x + rd.y;
        }
        __syncthreads();
        #pragma unroll
        for (int r = 0; r < 2; ++r) {
            int idx = tid + r * 1024;
            int g = idx >> 8, dd = idx & 255;
            float s = rdlds[g][0][dd] + rdlds[g][1][dd] + rdlds[g][2][dd] + rdlds[g][3][dd];
            reads_buf[(rb + t0 + g) * DVv + dd] = s;
        }
        __syncthreads();
    }
    if (!last) {
        #pragma unroll
        for (int i = 0; i < 16; ++i)
            *reinterpret_cast<f32x2*>(&state[((size_t)b * DVv + d) * MM + m0 + 2 * i]) = mem[i];
    }
}

// ---------------------------------------------------------------- k4: logits (fp32)
__global__ __launch_bounds__(256) void k4_final(const int* __restrict__ q_data,
                                                const float* __restrict__ q_tab,
                                                const float* __restrict__ reads_buf,
                                                const float* __restrict__ W_rd,
                                                const float* __restrict__ b_rd,
                                                const float* __restrict__ W_pr,
                                                const float* __restrict__ b_pr,
                                                float* __restrict__ out,
                                                int tcs, int tcm, int coff) {
    __shared__ float A[32][36];
    __shared__ float BT[32][132];
    __shared__ int qidx[32];
    int t = threadIdx.x;
    int row0 = blockIdx.x * 32;
    if (t < 32) {
        int rl = row0 + t;
        qidx[t] = q_data[(rl >> tcs) * SS + coff + (rl & tcm)];
    }
    int rg = t >> 5, cg = t & 31;
    float acc[4][4];
    #pragma unroll
    for (int i = 0; i < 4; ++i)
        #pragma unroll
        for (int j = 0; j < 4; ++j) acc[i][j] = 0.f;

    for (int ks = 0; ks < 384; ks += 32) {
        __syncthreads();
        {
            int r = t >> 3, k4 = t & 7;
            int kg = ks + k4 * 4;
            float4 v;
            if (kg < 256)
                v = *reinterpret_cast<const float4*>(reads_buf + (size_t)(row0 + r) * DVv + kg);
            else
                v = *reinterpret_cast<const float4*>(q_tab + (size_t)qidx[r] * DKk + (kg - 256));
            *reinterpret_cast<float4*>(&A[r][k4 * 4]) = v;
        }
        #pragma unroll
        for (int i = 0; i < 4; ++i) {
            int f = t + 256 * i;
            int c = f >> 3, k4 = f & 7;
            float4 v = *reinterpret_cast<const float4*>(W_rd + (size_t)c * 384 + ks + k4 * 4);
            BT[k4 * 4 + 0][c] = v.x;
            BT[k4 * 4 + 1][c] = v.y;
            BT[k4 * 4 + 2][c] = v.z;
            BT[k4 * 4 + 3][c] = v.w;
        }
        __syncthreads();
        for (int k = 0; k < 32; k += 4) {
            float a_[4][4];
            #pragma unroll
            for (int i = 0; i < 4; ++i) {
                float4 v = *reinterpret_cast<const float4*>(&A[rg * 4 + i][k]);
                a_[i][0] = v.x; a_[i][1] = v.y; a_[i][2] = v.z; a_[i][3] = v.w;
            }
            #pragma unroll
            for (int kk = 0; kk < 4; ++kk) {
                float4 b = *reinterpret_cast<const float4*>(&BT[k + kk][cg * 4]);
                #pragma unroll
                for (int i = 0; i < 4; ++i) {
                    float av = a_[i][kk];
                    acc[i][0] = fmaf(av, b.x, acc[i][0]);
                    acc[i][1] = fmaf(av, b.y, acc[i][1]);
                    acc[i][2] = fmaf(av, b.z, acc[i][2]);
                    acc[i][3] = fmaf(av, b.w, acc[i][3]);
                }
            }
        }
    }
    float h[4][4];
    #pragma unroll
    for (int i = 0; i < 4; ++i)
        #pragma unroll
        for (int j = 0; j < 4; ++j)
            h[i][j] = tanhf(acc[i][j] + b_rd[cg * 4 + j]);
    __syncthreads();
    #pragma unroll
    for (int i = 0; i < 4; ++i)
        *reinterpret_cast<float4*>(&BT[rg * 4 + i][cg * 4]) =
            make_float4(h[i][0], h[i][1], h[i][2], h[i][3]);
    __syncthreads();
    int wv = t >> 6, lane = t & 63;
    float2 wp = *reinterpret_cast<const float2*>(W_pr + 2 * lane);
    float bp = b_pr[0];
    for (int rr = 0; rr < 8; ++rr) {
        int r = wv * 8 + rr;
        float2 h2 = *reinterpret_cast<const float2*>(&BT[r][2 * lane]);
        float s = h2.x * wp.x + h2.y * wp.y;
        for (int off = 1; off < 64; off <<= 1) s += __shfl_xor(s, off, 64);
        if (lane == 0) {
            int rl = row0 + r;
            out[(rl >> tcs) * SS + coff + (rl & tcm)] = s + bp;
        }
    }
}

// ---------------------------------------------------------------- launch
extern "C" void kernel_launch(void* const* d_in, const int* in_sizes, int n_in,
                              void* d_out, int out_size, void* d_ws, size_t ws_size,
                              hipStream_t stream) {
    const int*   q_data   = (const int*)d_in[0];
    const int*   qa_data  = (const int*)d_in[1];
    const float* q_tab    = (const float*)d_in[2];
    const float* qa_tab   = (const float*)d_in[3];
    const float* mk       = (const float*)d_in[4];
    const float* init_mem = (const float*)d_in[5];
    const float* W_er     = (const float*)d_in[6];
    const float* b_er     = (const float*)d_in[7];
    const float* W_ad     = (const float*)d_in[8];
    const float* b_ad     = (const float*)d_in[9];
    const float* W_rd     = (const float*)d_in[10];
    const float* b_rd     = (const float*)d_in[11];
    const float* W_pr     = (const float*)d_in[12];
    const float* b_pr     = (const float*)d_in[13];
    float* out = (float*)d_out;

    const size_t state_f = (size_t)BB * MM * DVv;          // 8,388,608 floats
    const size_t qa16_n  = (size_t)20001 * 256;            // ushorts
    const size_t wea16_n = 131072;                         // ushorts
    const size_t bf16_f  = (qa16_n + wea16_n + 1) / 2 + 8; // float-equivalents

    size_t avail_f = ws_size / 4;
    int TC = 8;
    {
        const int cand[] = {512, 256, 128, 64, 32, 16, 8};
        for (int i = 0; i < 7; ++i) {
            size_t need = 16384 + state_f + bf16_f + (size_t)BB * cand[i] * (MM + 512 + DVv);
            if (need <= avail_f) { TC = cand[i]; break; }
        }
    }
    int NC = SS / TC;
    int tcs = __builtin_ctz(TC);
    int tcm = TC - 1;

    float* ws      = (float*)d_ws;
    float* mkt     = ws;                                    // 16384
    float* state   = mkt + 16384;
    float* w_buf   = state + state_f;                       // B*TC*128
    float* ea_buf  = w_buf + (size_t)BB * TC * MM;          // B*TC*512
    float* reads   = ea_buf + (size_t)BB * TC * 512;        // B*TC*256
    unsigned short* qa16  = (unsigned short*)(reads + (size_t)BB * TC * DVv);
    unsigned short* wea16 = qa16 + qa16_n;

    kt_transpose<<<64, 256, 0, stream>>>(mk, mkt);
    kcvt<<<1024, 256, 0, stream>>>(qa_tab, W_er, W_ad, qa16, wea16);
    for (int c = 0; c < NC; ++c) {
        int coff = c * TC;
        int rows = BB * TC;
        k1_scores<<<rows / 64, 256, 0, stream>>>(q_data, q_tab, mkt, w_buf, tcs, tcm, coff);
        k2_ea_mfma<<<(rows / 128) * 4, 256, 0, stream>>>(qa_data, qa16, wea16, b_er, b_ad,
                                                         ea_buf, tcs, tcm, coff);
        k3_seq<<<BB, 1024, 0, stream>>>(w_buf, ea_buf, init_mem, state, reads,
                                        TC, c == 0, c == NC - 1);
        k4_final<<<rows / 32, 256, 0, stream>>>(q_data, q_tab, reads, W_rd, b_rd, W_pr, b_pr,
                                                out, tcs, tcm, coff);
    }
}

// Round 6
// 625.882 us; speedup vs baseline: 2.5724x; 1.4560x over previous
//
#include <hip/hip_runtime.h>
#include <hip/hip_bf16.h>

// DKVMN forward. B=256 S=512 M=128 DK=128 DV=256 FC=128.
// Chunked over time (TC chosen to fit ws_size). Per chunk:
//   k1 (fp32): w = softmax(qe @ MK^T)
//   k2 (bf16 MFMA): e|a = act(qa @ [We|Wa]^T)
//   k3: sequential read/update; mem in VGPRs (f32x2 pk ops); w staged to LDS
//       8 steps at a time (double-buffered), uniform ds_read broadcast;
//       reads written bf16
//   k4 (bf16 MFMA): logits = Wp @ tanh(Wr @ [read|qe])

#define BB    256
#define SS    512
#define MM    128
#define DKk   128
#define DVv   256

typedef float  f32x2  __attribute__((ext_vector_type(2)));
typedef float  f32x4  __attribute__((ext_vector_type(4)));
typedef short  bf16x8 __attribute__((ext_vector_type(8)));

static __device__ __forceinline__ unsigned short f2bf(float f) {
    unsigned u = __float_as_uint(f);
    unsigned r = (u + 0x7FFFu + ((u >> 16) & 1u)) >> 16;
    return (unsigned short)r;
}
static __device__ __forceinline__ float fast_tanh(float x) {
    float ex = __expf(2.f * x);
    return 1.f - 2.f / (ex + 1.f);
}
static __device__ __forceinline__ float fast_sigmoid(float x) {
    return 1.f / (1.f + __expf(-x));
}

// ---------------------------------------------------------------- transpose MK (fp32, for k1)
__global__ __launch_bounds__(256) void kt_transpose(const float* __restrict__ mk,
                                                    float* __restrict__ mkt) {
    int idx = blockIdx.x * 256 + threadIdx.x;   // 64 blocks
    int m = idx >> 7, k = idx & 127;
    mkt[(size_t)k * MM + m] = mk[(size_t)m * DKk + k];
}

// ---------------------------------------------------------------- convert tables to bf16
// n_qa / n_q come from in_sizes (qa table = 20001*256, q table = 10001*128).
__global__ __launch_bounds__(256) void kcvt(const float* __restrict__ qa_tab,
                                            const float* __restrict__ q_tab,
                                            const float* __restrict__ W_er,
                                            const float* __restrict__ W_ad,
                                            const float* __restrict__ W_rd,
                                            unsigned short* __restrict__ qa16,
                                            unsigned short* __restrict__ q16,
                                            unsigned short* __restrict__ wea16,
                                            unsigned short* __restrict__ wrd16,
                                            int n_qa, int n_q) {
    for (int i = blockIdx.x * 256 + threadIdx.x; i < n_qa; i += gridDim.x * 256)
        qa16[i] = f2bf(qa_tab[i]);
    for (int i = blockIdx.x * 256 + threadIdx.x; i < n_q; i += gridDim.x * 256)
        q16[i] = f2bf(q_tab[i]);
    for (int i = blockIdx.x * 256 + threadIdx.x; i < 65536; i += gridDim.x * 256) {
        wea16[i] = f2bf(W_er[i]);
        wea16[65536 + i] = f2bf(W_ad[i]);
    }
    for (int i = blockIdx.x * 256 + threadIdx.x; i < 49152; i += gridDim.x * 256)
        wrd16[i] = f2bf(W_rd[i]);
}

// ---------------------------------------------------------------- k1: w = softmax(qe @ MK^T)  (fp32)
__global__ __launch_bounds__(256) void k1_scores(const int* __restrict__ q_data,
                                                 const float* __restrict__ q_tab,
                                                 const float* __restrict__ mkt,
                                                 float* __restrict__ w_buf,
                                                 int tcs, int tcm, int coff) {
    __shared__ float A[64][132];
    __shared__ int qidx[64];
    int t = threadIdx.x;
    int row0 = blockIdx.x * 64;
    if (t < 64) {
        int rl = row0 + t;
        qidx[t] = q_data[(rl >> tcs) * SS + coff + (rl & tcm)];
    }
    __syncthreads();
    #pragma unroll
    for (int i = 0; i < 8; ++i) {
        int f = t + 256 * i;
        int r = f >> 5, c4 = f & 31;
        float4 v = *reinterpret_cast<const float4*>(q_tab + (size_t)qidx[r] * DKk + c4 * 4);
        *reinterpret_cast<float4*>(&A[r][c4 * 4]) = v;
    }
    __syncthreads();
    int rg = t >> 4, cg = t & 15;
    float acc[4][8];
    #pragma unroll
    for (int i = 0; i < 4; ++i)
        #pragma unroll
        for (int j = 0; j < 8; ++j) acc[i][j] = 0.f;

    for (int k = 0; k < 128; k += 4) {
        float a_[4][4];
        #pragma unroll
        for (int i = 0; i < 4; ++i) {
            float4 v = *reinterpret_cast<const float4*>(&A[rg * 4 + i][k]);
            a_[i][0] = v.x; a_[i][1] = v.y; a_[i][2] = v.z; a_[i][3] = v.w;
        }
        #pragma unroll
        for (int kk = 0; kk < 4; ++kk) {
            const float* bp = mkt + (size_t)(k + kk) * MM + cg * 8;
            float4 b0 = *reinterpret_cast<const float4*>(bp);
            float4 b1 = *reinterpret_cast<const float4*>(bp + 4);
            #pragma unroll
            for (int i = 0; i < 4; ++i) {
                float av = a_[i][kk];
                acc[i][0] = fmaf(av, b0.x, acc[i][0]);
                acc[i][1] = fmaf(av, b0.y, acc[i][1]);
                acc[i][2] = fmaf(av, b0.z, acc[i][2]);
                acc[i][3] = fmaf(av, b0.w, acc[i][3]);
                acc[i][4] = fmaf(av, b1.x, acc[i][4]);
                acc[i][5] = fmaf(av, b1.y, acc[i][5]);
                acc[i][6] = fmaf(av, b1.z, acc[i][6]);
                acc[i][7] = fmaf(av, b1.w, acc[i][7]);
            }
        }
    }
    #pragma unroll
    for (int i = 0; i < 4; ++i) {
        float mx = acc[i][0];
        #pragma unroll
        for (int j = 1; j < 8; ++j) mx = fmaxf(mx, acc[i][j]);
        for (int off = 1; off < 16; off <<= 1) mx = fmaxf(mx, __shfl_xor(mx, off, 64));
        float s = 0.f;
        #pragma unroll
        for (int j = 0; j < 8; ++j) { float p = __expf(acc[i][j] - mx); acc[i][j] = p; s += p; }
        for (int off = 1; off < 16; off <<= 1) s += __shfl_xor(s, off, 64);
        float inv = 1.f / s;
        #pragma unroll
        for (int j = 0; j < 8; ++j) acc[i][j] *= inv;
        size_t ro = (size_t)(row0 + rg * 4 + i) * MM + cg * 8;
        *reinterpret_cast<float4*>(w_buf + ro)     = make_float4(acc[i][0], acc[i][1], acc[i][2], acc[i][3]);
        *reinterpret_cast<float4*>(w_buf + ro + 4) = make_float4(acc[i][4], acc[i][5], acc[i][6], acc[i][7]);
    }
}

// ---------------------------------------------------------------- k2: e|a via bf16 MFMA
__global__ __launch_bounds__(256) void k2_ea_mfma(const int* __restrict__ qa_data,
                                                  const unsigned short* __restrict__ qa16,
                                                  const unsigned short* __restrict__ wea16,
                                                  const float* __restrict__ b_er,
                                                  const float* __restrict__ b_ad,
                                                  float* __restrict__ ea_buf,
                                                  int tcs, int tcm, int coff) {
    __shared__ __align__(16) unsigned short A_lds[128 * 64];
    __shared__ int qidx[128];
    int t = threadIdx.x;
    int rb = blockIdx.x >> 2, cb = blockIdx.x & 3;
    int row0 = rb * 128;
    if (t < 128) {
        int rl = row0 + t;
        qidx[t] = qa_data[(rl >> tcs) * SS + coff + (rl & tcm)];
    }
    int l = t & 63;
    int wid = t >> 6, wr = wid >> 1, wc = wid & 1;
    f32x4 acc[4][4];
    #pragma unroll
    for (int i = 0; i < 4; ++i)
        #pragma unroll
        for (int j = 0; j < 4; ++j)
            acc[i][j] = (f32x4){0.f, 0.f, 0.f, 0.f};

    for (int ks = 0; ks < 256; ks += 64) {
        __syncthreads();
        #pragma unroll
        for (int p = 0; p < 4; ++p) {
            int U = p * 256 + t;
            int r = U >> 3, kb = U & 7;
            int kb_log = kb ^ (r & 7);
            int4 v = *reinterpret_cast<const int4*>(qa16 + (size_t)qidx[r] * 256 + ks + kb_log * 8);
            *reinterpret_cast<int4*>(&A_lds[U * 8]) = v;
        }
        __syncthreads();
        #pragma unroll
        for (int ksub = 0; ksub < 2; ++ksub) {
            bf16x8 af[4];
            #pragma unroll
            for (int mi = 0; mi < 4; ++mi) {
                int r = wr * 64 + mi * 16 + (l & 15);
                int kb_log = ksub * 4 + (l >> 4);
                int pu = r * 8 + (kb_log ^ (r & 7));
                af[mi] = *reinterpret_cast<const bf16x8*>(&A_lds[pu * 8]);
            }
            #pragma unroll
            for (int nj = 0; nj < 4; ++nj) {
                int col = cb * 128 + wc * 64 + nj * 16 + (l & 15);
                bf16x8 bf = *reinterpret_cast<const bf16x8*>(
                    wea16 + (size_t)col * 256 + ks + ksub * 32 + (l >> 4) * 8);
                #pragma unroll
                for (int mi = 0; mi < 4; ++mi)
                    acc[mi][nj] = __builtin_amdgcn_mfma_f32_16x16x32_bf16(af[mi], bf, acc[mi][nj], 0, 0, 0);
            }
        }
    }
    #pragma unroll
    for (int nj = 0; nj < 4; ++nj) {
        int col = cb * 128 + wc * 64 + nj * 16 + (l & 15);
        bool is_e = (cb < 2);
        float bias = is_e ? b_er[col] : b_ad[col - 256];
        #pragma unroll
        for (int mi = 0; mi < 4; ++mi) {
            #pragma unroll
            for (int reg = 0; reg < 4; ++reg) {
                int rl = row0 + wr * 64 + mi * 16 + (l >> 4) * 4 + reg;
                float x = acc[mi][nj][reg] + bias;
                float y = is_e ? fast_sigmoid(x) : fast_tanh(x);
                ea_buf[(size_t)rl * 512 + col] = y;
            }
        }
    }
}

// ---------------------------------------------------------------- k3: sequential read/update
// 1 block (1024 thr = 16 waves) per batch; wave (mq,dq); mem 16x f32x2 over m-pairs.
// w staged to LDS for 8 steps at a time (double-buffered, global loads issued one
// batch ahead); per-step uniform ds_read_b128 broadcast. reads written bf16.
__global__ __launch_bounds__(1024, 1) void k3_seq(const float* __restrict__ w_buf,
                                                  const float* __restrict__ ea_buf,
                                                  const float* __restrict__ init_mem,
                                                  float* __restrict__ state,
                                                  unsigned short* __restrict__ reads16,
                                                  int TC, int first, int last) {
    __shared__ float wlds[2][8][128];
    __shared__ float rdlds[8][4][256];
    int b = blockIdx.x;
    int tid = threadIdx.x;
    int wv = tid >> 6, lane = tid & 63;
    int mq = wv >> 2, dq = wv & 3;
    int d = dq * 64 + lane;
    int m0 = mq * 32;
    f32x2 mem[16];
    if (first) {
        #pragma unroll
        for (int i = 0; i < 16; ++i) {
            mem[i].x = init_mem[(size_t)(m0 + 2 * i) * DVv + d];
            mem[i].y = init_mem[(size_t)(m0 + 2 * i + 1) * DVv + d];
        }
    } else {
        #pragma unroll
        for (int i = 0; i < 16; ++i)
            mem[i] = *reinterpret_cast<const f32x2*>(&state[((size_t)b * DVv + d) * MM + m0 + 2 * i]);
    }
    size_t rb = (size_t)b * TC;
    int gg = tid >> 7, mm = tid & 127;
    // stage batch 0
    wlds[0][gg][mm] = w_buf[(rb + gg) * MM + mm];
    __syncthreads();
    for (int t0 = 0; t0 < TC; t0 += 8) {
        int cur = (t0 >> 3) & 1, nxt = cur ^ 1;
        // issue next-batch w load (HBM latency hides under this batch's compute)
        bool havenext = (t0 + 8) < TC;
        float wn = 0.f;
        if (havenext) wn = w_buf[(rb + t0 + 8 + gg) * MM + mm];
        // prefetch e/a for all 8 steps
        float e8[8], a8[8];
        #pragma unroll
        for (int g = 0; g < 8; ++g) {
            size_t rr = (rb + t0 + g) * 512;
            e8[g] = ea_buf[rr + d];
            a8[g] = ea_buf[rr + 256 + d];
        }
        #pragma unroll
        for (int g = 0; g < 8; ++g) {
            const f32x4* wp4 = reinterpret_cast<const f32x4*>(&wlds[cur][g][m0]);
            f32x2 rd; rd.x = 0.f; rd.y = 0.f;
            f32x2 ne2; ne2.x = -e8[g]; ne2.y = -e8[g];
            f32x2 a2;  a2.x = a8[g];  a2.y = a8[g];
            #pragma unroll
            for (int j = 0; j < 8; ++j) {
                f32x4 w4 = wp4[j];                       // uniform ds_read_b128 broadcast
                f32x2 wlo; wlo.x = w4.x; wlo.y = w4.y;
                f32x2 whi; whi.x = w4.z; whi.y = w4.w;
                f32x2 tt;
                asm("v_pk_fma_f32 %0, %1, %2, %0" : "+v"(rd)          : "v"(wlo), "v"(mem[2*j]));
                asm("v_pk_fma_f32 %0, %1, %2, %3" : "=v"(tt)          : "v"(ne2), "v"(mem[2*j]), "v"(a2));
                asm("v_pk_fma_f32 %0, %1, %2, %0" : "+v"(mem[2*j])    : "v"(wlo), "v"(tt));
                asm("v_pk_fma_f32 %0, %1, %2, %0" : "+v"(rd)          : "v"(whi), "v"(mem[2*j+1]));
                asm("v_pk_fma_f32 %0, %1, %2, %3" : "=v"(tt)          : "v"(ne2), "v"(mem[2*j+1]), "v"(a2));
                asm("v_pk_fma_f32 %0, %1, %2, %0" : "+v"(mem[2*j+1])  : "v"(whi), "v"(tt));
            }
            rdlds[g][mq][d] = rd.x + rd.y;
        }
        __syncthreads();
        // write next w batch to LDS; combine partial reads -> bf16
        if (havenext) wlds[nxt][gg][mm] = wn;
        #pragma unroll
        for (int r = 0; r < 2; ++r) {
            int idx = tid + r * 1024;
            int g = idx >> 8, dd = idx & 255;
            float s = rdlds[g][0][dd] + rdlds[g][1][dd] + rdlds[g][2][dd] + rdlds[g][3][dd];
            reads16[(rb + t0 + g) * DVv + dd] = f2bf(s);
        }
        __syncthreads();
    }
    if (!last) {
        #pragma unroll
        for (int i = 0; i < 16; ++i)
            *reinterpret_cast<f32x2*>(&state[((size_t)b * DVv + d) * MM + m0 + 2 * i]) = mem[i];
    }
}

// ---------------------------------------------------------------- k4: logits via bf16 MFMA
// tile 128 rows x 128 cols (FC), 4 waves (2x2); K=384 over [reads16 | qe16];
// epilogue: h=tanh(acc+b_rd) fp32, dot with W_pr (fp32), out.
__global__ __launch_bounds__(256) void k4_mfma(const int* __restrict__ q_data,
                                               const unsigned short* __restrict__ q16,
                                               const unsigned short* __restrict__ reads16,
                                               const unsigned short* __restrict__ wrd16,
                                               const float* __restrict__ b_rd,
                                               const float* __restrict__ W_pr,
                                               const float* __restrict__ b_pr,
                                               float* __restrict__ out,
                                               int tcs, int tcm, int coff) {
    __shared__ __align__(16) unsigned short A_lds[128 * 64];
    __shared__ int qidx[128];
    __shared__ float plds[2][128];
    int t = threadIdx.x;
    int row0 = blockIdx.x * 128;
    if (t < 128) {
        int rl = row0 + t;
        qidx[t] = q_data[(rl >> tcs) * SS + coff + (rl & tcm)];
    }
    int l = t & 63;
    int wid = t >> 6, wr = wid >> 1, wc = wid & 1;
    f32x4 acc[4][4];
    #pragma unroll
    for (int i = 0; i < 4; ++i)
        #pragma unroll
        for (int j = 0; j < 4; ++j)
            acc[i][j] = (f32x4){0.f, 0.f, 0.f, 0.f};

    for (int ks = 0; ks < 384; ks += 64) {
        __syncthreads();
        #pragma unroll
        for (int p = 0; p < 4; ++p) {
            int U = p * 256 + t;
            int r = U >> 3, kb = U & 7;
            int kb_log = kb ^ (r & 7);
            int kg = ks + kb_log * 8;
            const unsigned short* src = (kg < 256)
                ? (reads16 + (size_t)(row0 + r) * DVv + kg)
                : (q16 + (size_t)qidx[r] * DKk + (kg - 256));
            int4 v = *reinterpret_cast<const int4*>(src);
            *reinterpret_cast<int4*>(&A_lds[U * 8]) = v;
        }
        __syncthreads();
        #pragma unroll
        for (int ksub = 0; ksub < 2; ++ksub) {
            bf16x8 af[4];
            #pragma unroll
            for (int mi = 0; mi < 4; ++mi) {
                int r = wr * 64 + mi * 16 + (l & 15);
                int kb_log = ksub * 4 + (l >> 4);
                int pu = r * 8 + (kb_log ^ (r & 7));
                af[mi] = *reinterpret_cast<const bf16x8*>(&A_lds[pu * 8]);
            }
            #pragma unroll
            for (int nj = 0; nj < 4; ++nj) {
                int col = wc * 64 + nj * 16 + (l & 15);
                bf16x8 bf = *reinterpret_cast<const bf16x8*>(
                    wrd16 + (size_t)col * 384 + ks + ksub * 32 + (l >> 4) * 8);
                #pragma unroll
                for (int mi = 0; mi < 4; ++mi)
                    acc[mi][nj] = __builtin_amdgcn_mfma_f32_16x16x32_bf16(af[mi], bf, acc[mi][nj], 0, 0, 0);
            }
        }
    }
    // epilogue: h = tanh(acc + b_rd[col]); partial dot with W_pr
    float part[16];
    #pragma unroll
    for (int k = 0; k < 16; ++k) part[k] = 0.f;
    #pragma unroll
    for (int nj = 0; nj < 4; ++nj) {
        int col = wc * 64 + nj * 16 + (l & 15);
        float bias = b_rd[col];
        float wpr = W_pr[col];
        #pragma unroll
        for (int mi = 0; mi < 4; ++mi) {
            #pragma unroll
            for (int reg = 0; reg < 4; ++reg) {
                float h = fast_tanh(acc[mi][nj][reg] + bias);
                part[mi * 4 + reg] = fmaf(h, wpr, part[mi * 4 + reg]);
            }
        }
    }
    #pragma unroll
    for (int k = 0; k < 16; ++k) {
        #pragma unroll
        for (int off = 1; off < 16; off <<= 1)
            part[k] += __shfl_xor(part[k], off, 64);
    }
    if ((l & 15) == 0) {
        #pragma unroll
        for (int mi = 0; mi < 4; ++mi)
            #pragma unroll
            for (int reg = 0; reg < 4; ++reg) {
                int row = wr * 64 + mi * 16 + (l >> 4) * 4 + reg;
                plds[wc][row] = part[mi * 4 + reg];
            }
    }
    __syncthreads();
    if (t < 128) {
        float s = plds[0][t] + plds[1][t] + b_pr[0];
        int rl = row0 + t;
        out[(rl >> tcs) * SS + coff + (rl & tcm)] = s;
    }
}

// ---------------------------------------------------------------- launch
extern "C" void kernel_launch(void* const* d_in, const int* in_sizes, int n_in,
                              void* d_out, int out_size, void* d_ws, size_t ws_size,
                              hipStream_t stream) {
    const int*   q_data   = (const int*)d_in[0];
    const int*   qa_data  = (const int*)d_in[1];
    const float* q_tab    = (const float*)d_in[2];
    const float* qa_tab   = (const float*)d_in[3];
    const float* mk       = (const float*)d_in[4];
    const float* init_mem = (const float*)d_in[5];
    const float* W_er     = (const float*)d_in[6];
    const float* b_er     = (const float*)d_in[7];
    const float* W_ad     = (const float*)d_in[8];
    const float* b_ad     = (const float*)d_in[9];
    const float* W_rd     = (const float*)d_in[10];
    const float* b_rd     = (const float*)d_in[11];
    const float* W_pr     = (const float*)d_in[12];
    const float* b_pr     = (const float*)d_in[13];
    float* out = (float*)d_out;

    const size_t state_f = (size_t)BB * MM * DVv;          // 8,388,608 floats
    const size_t qa16_n  = (size_t)in_sizes[3];            // 20001*256 ushorts
    const size_t q16_n   = (size_t)in_sizes[2];            // 10001*128 ushorts
    const size_t wea16_n = 131072;
    const size_t wrd16_n = 49152;
    const size_t bf16_f  = (qa16_n + q16_n + wea16_n + wrd16_n) / 2 + 16;

    size_t avail_f = ws_size / 4;
    int TC = 8;
    {
        const int cand[] = {512, 256, 128, 64, 32, 16, 8};
        for (int i = 0; i < 7; ++i) {
            // per-chunk floats: w(128) + ea(512) + reads16(256 us = 128 f)
            size_t need = 16384 + state_f + bf16_f + (size_t)BB * cand[i] * (MM + 512 + 128);
            if (need <= avail_f) { TC = cand[i]; break; }
        }
    }
    int NC = SS / TC;
    int tcs = __builtin_ctz(TC);
    int tcm = TC - 1;

    float* ws      = (float*)d_ws;
    float* mkt     = ws;                                    // 16384
    float* state   = mkt + 16384;
    float* w_buf   = state + state_f;                       // B*TC*128
    float* ea_buf  = w_buf + (size_t)BB * TC * MM;          // B*TC*512
    unsigned short* reads16 = (unsigned short*)(ea_buf + (size_t)BB * TC * 512); // B*TC*256 us
    unsigned short* qa16  = reads16 + (size_t)BB * TC * DVv;
    unsigned short* q16   = qa16 + qa16_n;
    unsigned short* wea16 = q16 + q16_n;
    unsigned short* wrd16 = wea16 + wea16_n;

    kt_transpose<<<64, 256, 0, stream>>>(mk, mkt);
    kcvt<<<1024, 256, 0, stream>>>(qa_tab, q_tab, W_er, W_ad, W_rd, qa16, q16, wea16, wrd16,
                                   (int)qa16_n, (int)q16_n);
    for (int c = 0; c < NC; ++c) {
        int coff = c * TC;
        int rows = BB * TC;
        k1_scores<<<rows / 64, 256, 0, stream>>>(q_data, q_tab, mkt, w_buf, tcs, tcm, coff);
        k2_ea_mfma<<<(rows / 128) * 4, 256, 0, stream>>>(qa_data, qa16, wea16, b_er, b_ad,
                                                         ea_buf, tcs, tcm, coff);
        k3_seq<<<BB, 1024, 0, stream>>>(w_buf, ea_buf, init_mem, state, reads16,
                                        TC, c == 0, c == NC - 1);
        k4_mfma<<<rows / 128, 256, 0, stream>>>(q_data, q16, reads16, wrd16, b_rd, W_pr, b_pr,
                                                out, tcs, tcm, coff);
    }
}

// Round 7
// 609.853 us; speedup vs baseline: 2.6400x; 1.0263x over previous
//
#include <hip/hip_runtime.h>
#include <hip/hip_bf16.h>

// DKVMN forward. B=256 S=512 M=128 DK=128 DV=256 FC=128.
// Chunked over time (TC chosen to fit ws_size). Per chunk:
//   k1 (bf16 MFMA): w = softmax(qe @ MK^T), fp32 softmax epilogue
//   k2 (bf16 MFMA): e|a = act(qa @ [We|Wa]^T), stored bf16
//   k3: sequential read/update; mem in VGPRs (f32x2 pk ops); w loaded per-lane
//       (1 dwordx4 per wave per 8 steps) and broadcast via v_readlane -> SGPR
//       pair feeding v_pk_fma scalar operand; reads written bf16
//   k4 (bf16 MFMA): logits = Wp @ tanh(Wr @ [read|qe])

#define BB    256
#define SS    512
#define MM    128
#define DKk   128
#define DVv   256

typedef float  f32x2  __attribute__((ext_vector_type(2)));
typedef float  f32x4  __attribute__((ext_vector_type(4)));
typedef short  bf16x8 __attribute__((ext_vector_type(8)));

static __device__ __forceinline__ unsigned short f2bf(float f) {
    unsigned u = __float_as_uint(f);
    unsigned r = (u + 0x7FFFu + ((u >> 16) & 1u)) >> 16;
    return (unsigned short)r;
}
static __device__ __forceinline__ float bf2f(unsigned short u) {
    return __uint_as_float(((unsigned)u) << 16);
}
static __device__ __forceinline__ float fast_tanh(float x) {
    float ex = __expf(2.f * x);
    return 1.f - 2.f / (ex + 1.f);
}
static __device__ __forceinline__ float fast_sigmoid(float x) {
    return 1.f / (1.f + __expf(-x));
}

// ---------------------------------------------------------------- convert tables to bf16
__global__ __launch_bounds__(256) void kcvt(const float* __restrict__ qa_tab,
                                            const float* __restrict__ q_tab,
                                            const float* __restrict__ W_er,
                                            const float* __restrict__ W_ad,
                                            const float* __restrict__ W_rd,
                                            const float* __restrict__ mk,
                                            unsigned short* __restrict__ qa16,
                                            unsigned short* __restrict__ q16,
                                            unsigned short* __restrict__ wea16,
                                            unsigned short* __restrict__ wrd16,
                                            unsigned short* __restrict__ mk16,
                                            int n_qa, int n_q) {
    for (int i = blockIdx.x * 256 + threadIdx.x; i < n_qa; i += gridDim.x * 256)
        qa16[i] = f2bf(qa_tab[i]);
    for (int i = blockIdx.x * 256 + threadIdx.x; i < n_q; i += gridDim.x * 256)
        q16[i] = f2bf(q_tab[i]);
    for (int i = blockIdx.x * 256 + threadIdx.x; i < 65536; i += gridDim.x * 256) {
        wea16[i] = f2bf(W_er[i]);
        wea16[65536 + i] = f2bf(W_ad[i]);
    }
    for (int i = blockIdx.x * 256 + threadIdx.x; i < 49152; i += gridDim.x * 256)
        wrd16[i] = f2bf(W_rd[i]);
    for (int i = blockIdx.x * 256 + threadIdx.x; i < 16384; i += gridDim.x * 256)
        mk16[i] = f2bf(mk[i]);
}

// ---------------------------------------------------------------- k1: w = softmax(qe @ MK^T) via bf16 MFMA
// block 256 thr = 4 waves; wave wid owns 32 rows x 128 cols; K=128 in 2 slices.
__global__ __launch_bounds__(256) void k1_mfma(const int* __restrict__ q_data,
                                               const unsigned short* __restrict__ q16,
                                               const unsigned short* __restrict__ mk16,
                                               float* __restrict__ w_buf,
                                               int tcs, int tcm, int coff) {
    __shared__ __align__(16) unsigned short A_lds[128 * 64];
    __shared__ int qidx[128];
    int t = threadIdx.x;
    int row0 = blockIdx.x * 128;
    if (t < 128) {
        int rl = row0 + t;
        qidx[t] = q_data[(rl >> tcs) * SS + coff + (rl & tcm)];
    }
    int l = t & 63;
    int wid = t >> 6;
    f32x4 acc[2][8];
    #pragma unroll
    for (int i = 0; i < 2; ++i)
        #pragma unroll
        for (int j = 0; j < 8; ++j)
            acc[i][j] = (f32x4){0.f, 0.f, 0.f, 0.f};

    for (int ks = 0; ks < 128; ks += 64) {
        __syncthreads();
        #pragma unroll
        for (int p = 0; p < 4; ++p) {
            int U = p * 256 + t;
            int r = U >> 3, kb = U & 7;
            int kb_log = kb ^ (r & 7);
            int4 v = *reinterpret_cast<const int4*>(q16 + (size_t)qidx[r] * DKk + ks + kb_log * 8);
            *reinterpret_cast<int4*>(&A_lds[U * 8]) = v;
        }
        __syncthreads();
        #pragma unroll
        for (int ksub = 0; ksub < 2; ++ksub) {
            bf16x8 af[2];
            #pragma unroll
            for (int mi = 0; mi < 2; ++mi) {
                int r = wid * 32 + mi * 16 + (l & 15);
                int kb_log = ksub * 4 + (l >> 4);
                int pu = r * 8 + (kb_log ^ (r & 7));
                af[mi] = *reinterpret_cast<const bf16x8*>(&A_lds[pu * 8]);
            }
            #pragma unroll
            for (int nj = 0; nj < 8; ++nj) {
                int col = nj * 16 + (l & 15);
                bf16x8 bf = *reinterpret_cast<const bf16x8*>(
                    mk16 + (size_t)col * DKk + ks + ksub * 32 + (l >> 4) * 8);
                #pragma unroll
                for (int mi = 0; mi < 2; ++mi)
                    acc[mi][nj] = __builtin_amdgcn_mfma_f32_16x16x32_bf16(af[mi], bf, acc[mi][nj], 0, 0, 0);
            }
        }
    }
    // softmax per row (row spread over 8 nj regs x 16 lanes of same l>>4 group)
    #pragma unroll
    for (int mi = 0; mi < 2; ++mi) {
        #pragma unroll
        for (int reg = 0; reg < 4; ++reg) {
            float mx = acc[mi][0][reg];
            #pragma unroll
            for (int nj = 1; nj < 8; ++nj) mx = fmaxf(mx, acc[mi][nj][reg]);
            #pragma unroll
            for (int off = 1; off < 16; off <<= 1) mx = fmaxf(mx, __shfl_xor(mx, off, 64));
            float p[8], s = 0.f;
            #pragma unroll
            for (int nj = 0; nj < 8; ++nj) { p[nj] = __expf(acc[mi][nj][reg] - mx); s += p[nj]; }
            #pragma unroll
            for (int off = 1; off < 16; off <<= 1) s += __shfl_xor(s, off, 64);
            float inv = 1.f / s;
            int row = row0 + wid * 32 + mi * 16 + (l >> 4) * 4 + reg;
            #pragma unroll
            for (int nj = 0; nj < 8; ++nj)
                w_buf[(size_t)row * MM + nj * 16 + (l & 15)] = p[nj] * inv;
        }
    }
}

// ---------------------------------------------------------------- k2: e|a via bf16 MFMA (bf16 out)
__global__ __launch_bounds__(256) void k2_ea_mfma(const int* __restrict__ qa_data,
                                                  const unsigned short* __restrict__ qa16,
                                                  const unsigned short* __restrict__ wea16,
                                                  const float* __restrict__ b_er,
                                                  const float* __restrict__ b_ad,
                                                  unsigned short* __restrict__ ea16,
                                                  int tcs, int tcm, int coff) {
    __shared__ __align__(16) unsigned short A_lds[128 * 64];
    __shared__ int qidx[128];
    int t = threadIdx.x;
    int rb = blockIdx.x >> 2, cb = blockIdx.x & 3;
    int row0 = rb * 128;
    if (t < 128) {
        int rl = row0 + t;
        qidx[t] = qa_data[(rl >> tcs) * SS + coff + (rl & tcm)];
    }
    int l = t & 63;
    int wid = t >> 6, wr = wid >> 1, wc = wid & 1;
    f32x4 acc[4][4];
    #pragma unroll
    for (int i = 0; i < 4; ++i)
        #pragma unroll
        for (int j = 0; j < 4; ++j)
            acc[i][j] = (f32x4){0.f, 0.f, 0.f, 0.f};

    for (int ks = 0; ks < 256; ks += 64) {
        __syncthreads();
        #pragma unroll
        for (int p = 0; p < 4; ++p) {
            int U = p * 256 + t;
            int r = U >> 3, kb = U & 7;
            int kb_log = kb ^ (r & 7);
            int4 v = *reinterpret_cast<const int4*>(qa16 + (size_t)qidx[r] * 256 + ks + kb_log * 8);
            *reinterpret_cast<int4*>(&A_lds[U * 8]) = v;
        }
        __syncthreads();
        #pragma unroll
        for (int ksub = 0; ksub < 2; ++ksub) {
            bf16x8 af[4];
            #pragma unroll
            for (int mi = 0; mi < 4; ++mi) {
                int r = wr * 64 + mi * 16 + (l & 15);
                int kb_log = ksub * 4 + (l >> 4);
                int pu = r * 8 + (kb_log ^ (r & 7));
                af[mi] = *reinterpret_cast<const bf16x8*>(&A_lds[pu * 8]);
            }
            #pragma unroll
            for (int nj = 0; nj < 4; ++nj) {
                int col = cb * 128 + wc * 64 + nj * 16 + (l & 15);
                bf16x8 bf = *reinterpret_cast<const bf16x8*>(
                    wea16 + (size_t)col * 256 + ks + ksub * 32 + (l >> 4) * 8);
                #pragma unroll
                for (int mi = 0; mi < 4; ++mi)
                    acc[mi][nj] = __builtin_amdgcn_mfma_f32_16x16x32_bf16(af[mi], bf, acc[mi][nj], 0, 0, 0);
            }
        }
    }
    #pragma unroll
    for (int nj = 0; nj < 4; ++nj) {
        int col = cb * 128 + wc * 64 + nj * 16 + (l & 15);
        bool is_e = (cb < 2);
        float bias = is_e ? b_er[col] : b_ad[col - 256];
        #pragma unroll
        for (int mi = 0; mi < 4; ++mi) {
            #pragma unroll
            for (int reg = 0; reg < 4; ++reg) {
                int rl = row0 + wr * 64 + mi * 16 + (l >> 4) * 4 + reg;
                float x = acc[mi][nj][reg] + bias;
                float y = is_e ? fast_sigmoid(x) : fast_tanh(x);
                ea16[(size_t)rl * 512 + col] = f2bf(y);
            }
        }
    }
}

// ---------------------------------------------------------------- k3: sequential read/update
// 1 block (1024 thr = 16 waves) per batch; wave (mq,dq); mem 16x f32x2 over m-pairs.
// w: per-lane global dwordx4 per 8 steps; per-use broadcast via 2x v_readlane ->
// SGPR pair feeding v_pk_fma scalar operand (no LDS-pipe broadcasts).
__global__ __launch_bounds__(1024, 1) void k3_seq(const float* __restrict__ w_buf,
                                                  const unsigned short* __restrict__ ea16,
                                                  const float* __restrict__ init_mem,
                                                  float* __restrict__ state,
                                                  unsigned short* __restrict__ reads16,
                                                  int TC, int first, int last) {
    __shared__ float rdlds[8][4][256];
    int b = blockIdx.x;
    int tid = threadIdx.x;
    int wv = tid >> 6, lane = tid & 63;
    int mq = wv >> 2, dq = wv & 3;
    int d = dq * 64 + lane;
    int m0 = mq * 32;
    f32x2 mem[16];
    if (first) {
        #pragma unroll
        for (int i = 0; i < 16; ++i) {
            mem[i].x = init_mem[(size_t)(m0 + 2 * i) * DVv + d];
            mem[i].y = init_mem[(size_t)(m0 + 2 * i + 1) * DVv + d];
        }
    } else {
        #pragma unroll
        for (int i = 0; i < 16; ++i)
            mem[i] = *reinterpret_cast<const f32x2*>(&state[((size_t)b * DVv + d) * MM + m0 + 2 * i]);
    }
    size_t rb = (size_t)b * TC;
    for (int t0 = 0; t0 < TC; t0 += 8) {
        // per-lane w block: lane l holds w[t0 + (l>>3)][m0 + (l&7)*4 .. +3]
        f32x4 w4 = *reinterpret_cast<const f32x4*>(
            w_buf + (rb + t0 + (lane >> 3)) * MM + m0 + (lane & 7) * 4);
        // e/a for 8 steps (bf16 -> f32)
        float e8[8], a8[8];
        #pragma unroll
        for (int g = 0; g < 8; ++g) {
            const unsigned short* ep = ea16 + (rb + t0 + g) * 512;
            e8[g] = bf2f(ep[d]);
            a8[g] = bf2f(ep[256 + d]);
        }
        #pragma unroll
        for (int g = 0; g < 8; ++g) {
            f32x2 rd; rd.x = 0.f; rd.y = 0.f;
            f32x2 ne2; ne2.x = -e8[g]; ne2.y = -e8[g];
            f32x2 a2;  a2.x = a8[g];  a2.y = a8[g];
            #pragma unroll
            for (int i = 0; i < 16; ++i) {
                int src = 8 * g + (i >> 1);       // lane holding this pair
                int c = (i & 1) * 2;              // component offset
                f32x2 ws;
                ws.x = __uint_as_float((unsigned)__builtin_amdgcn_readlane(__float_as_uint(w4[c]), src));
                ws.y = __uint_as_float((unsigned)__builtin_amdgcn_readlane(__float_as_uint(w4[c + 1]), src));
                f32x2 tt;
                asm("v_pk_fma_f32 %0, %1, %2, %0" : "+v"(rd)     : "s"(ws), "v"(mem[i]));           // rd += w*mem
                asm("v_pk_fma_f32 %0, %1, %2, %3" : "=v"(tt)     : "v"(ne2), "v"(mem[i]), "v"(a2)); // tt = a - e*mem
                asm("v_pk_fma_f32 %0, %1, %2, %0" : "+v"(mem[i]) : "s"(ws), "v"(tt));               // mem += w*tt
            }
            rdlds[g][mq][d] = rd.x + rd.y;
        }
        __syncthreads();
        #pragma unroll
        for (int r = 0; r < 2; ++r) {
            int idx = tid + r * 1024;
            int g = idx >> 8, dd = idx & 255;
            float s = rdlds[g][0][dd] + rdlds[g][1][dd] + rdlds[g][2][dd] + rdlds[g][3][dd];
            reads16[(rb + t0 + g) * DVv + dd] = f2bf(s);
        }
        __syncthreads();
    }
    if (!last) {
        #pragma unroll
        for (int i = 0; i < 16; ++i)
            *reinterpret_cast<f32x2*>(&state[((size_t)b * DVv + d) * MM + m0 + 2 * i]) = mem[i];
    }
}

// ---------------------------------------------------------------- k4: logits via bf16 MFMA
__global__ __launch_bounds__(256) void k4_mfma(const int* __restrict__ q_data,
                                               const unsigned short* __restrict__ q16,
                                               const unsigned short* __restrict__ reads16,
                                               const unsigned short* __restrict__ wrd16,
                                               const float* __restrict__ b_rd,
                                               const float* __restrict__ W_pr,
                                               const float* __restrict__ b_pr,
                                               float* __restrict__ out,
                                               int tcs, int tcm, int coff) {
    __shared__ __align__(16) unsigned short A_lds[128 * 64];
    __shared__ int qidx[128];
    __shared__ float plds[2][128];
    int t = threadIdx.x;
    int row0 = blockIdx.x * 128;
    if (t < 128) {
        int rl = row0 + t;
        qidx[t] = q_data[(rl >> tcs) * SS + coff + (rl & tcm)];
    }
    int l = t & 63;
    int wid = t >> 6, wr = wid >> 1, wc = wid & 1;
    f32x4 acc[4][4];
    #pragma unroll
    for (int i = 0; i < 4; ++i)
        #pragma unroll
        for (int j = 0; j < 4; ++j)
            acc[i][j] = (f32x4){0.f, 0.f, 0.f, 0.f};

    for (int ks = 0; ks < 384; ks += 64) {
        __syncthreads();
        #pragma unroll
        for (int p = 0; p < 4; ++p) {
            int U = p * 256 + t;
            int r = U >> 3, kb = U & 7;
            int kb_log = kb ^ (r & 7);
            int kg = ks + kb_log * 8;
            const unsigned short* src = (kg < 256)
                ? (reads16 + (size_t)(row0 + r) * DVv + kg)
                : (q16 + (size_t)qidx[r] * DKk + (kg - 256));
            int4 v = *reinterpret_cast<const int4*>(src);
            *reinterpret_cast<int4*>(&A_lds[U * 8]) = v;
        }
        __syncthreads();
        #pragma unroll
        for (int ksub = 0; ksub < 2; ++ksub) {
            bf16x8 af[4];
            #pragma unroll
            for (int mi = 0; mi < 4; ++mi) {
                int r = wr * 64 + mi * 16 + (l & 15);
                int kb_log = ksub * 4 + (l >> 4);
                int pu = r * 8 + (kb_log ^ (r & 7));
                af[mi] = *reinterpret_cast<const bf16x8*>(&A_lds[pu * 8]);
            }
            #pragma unroll
            for (int nj = 0; nj < 4; ++nj) {
                int col = wc * 64 + nj * 16 + (l & 15);
                bf16x8 bf = *reinterpret_cast<const bf16x8*>(
                    wrd16 + (size_t)col * 384 + ks + ksub * 32 + (l >> 4) * 8);
                #pragma unroll
                for (int mi = 0; mi < 4; ++mi)
                    acc[mi][nj] = __builtin_amdgcn_mfma_f32_16x16x32_bf16(af[mi], bf, acc[mi][nj], 0, 0, 0);
            }
        }
    }
    float part[16];
    #pragma unroll
    for (int k = 0; k < 16; ++k) part[k] = 0.f;
    #pragma unroll
    for (int nj = 0; nj < 4; ++nj) {
        int col = wc * 64 + nj * 16 + (l & 15);
        float bias = b_rd[col];
        float wpr = W_pr[col];
        #pragma unroll
        for (int mi = 0; mi < 4; ++mi) {
            #pragma unroll
            for (int reg = 0; reg < 4; ++reg) {
                float h = fast_tanh(acc[mi][nj][reg] + bias);
                part[mi * 4 + reg] = fmaf(h, wpr, part[mi * 4 + reg]);
            }
        }
    }
    #pragma unroll
    for (int k = 0; k < 16; ++k) {
        #pragma unroll
        for (int off = 1; off < 16; off <<= 1)
            part[k] += __shfl_xor(part[k], off, 64);
    }
    if ((l & 15) == 0) {
        #pragma unroll
        for (int mi = 0; mi < 4; ++mi)
            #pragma unroll
            for (int reg = 0; reg < 4; ++reg) {
                int row = wr * 64 + mi * 16 + (l >> 4) * 4 + reg;
                plds[wc][row] = part[mi * 4 + reg];
            }
    }
    __syncthreads();
    if (t < 128) {
        float s = plds[0][t] + plds[1][t] + b_pr[0];
        int rl = row0 + t;
        out[(rl >> tcs) * SS + coff + (rl & tcm)] = s;
    }
}

// ---------------------------------------------------------------- launch
extern "C" void kernel_launch(void* const* d_in, const int* in_sizes, int n_in,
                              void* d_out, int out_size, void* d_ws, size_t ws_size,
                              hipStream_t stream) {
    const int*   q_data   = (const int*)d_in[0];
    const int*   qa_data  = (const int*)d_in[1];
    const float* q_tab    = (const float*)d_in[2];
    const float* qa_tab   = (const float*)d_in[3];
    const float* mk       = (const float*)d_in[4];
    const float* init_mem = (const float*)d_in[5];
    const float* W_er     = (const float*)d_in[6];
    const float* b_er     = (const float*)d_in[7];
    const float* W_ad     = (const float*)d_in[8];
    const float* b_ad     = (const float*)d_in[9];
    const float* W_rd     = (const float*)d_in[10];
    const float* b_rd     = (const float*)d_in[11];
    const float* W_pr     = (const float*)d_in[12];
    const float* b_pr     = (const float*)d_in[13];
    float* out = (float*)d_out;

    const size_t state_f = (size_t)BB * MM * DVv;          // 8,388,608 floats
    const size_t qa16_n  = (size_t)in_sizes[3];            // 20001*256 ushorts
    const size_t q16_n   = (size_t)in_sizes[2];            // 10001*128 ushorts
    const size_t wea16_n = 131072;
    const size_t wrd16_n = 49152;
    const size_t mk16_n  = 16384;
    const size_t bf16_f  = (qa16_n + q16_n + wea16_n + wrd16_n + mk16_n) / 2 + 32;

    size_t avail_f = ws_size / 4;
    int TC = 8;
    {
        const int cand[] = {512, 256, 128, 64, 32, 16, 8};
        for (int i = 0; i < 7; ++i) {
            // per-row floats: w(128 f32) + ea16(512 us = 256 f) + reads16(256 us = 128 f)
            size_t need = state_f + bf16_f + (size_t)BB * cand[i] * (MM + 256 + 128);
            if (need <= avail_f) { TC = cand[i]; break; }
        }
    }
    int NC = SS / TC;
    int tcs = __builtin_ctz(TC);
    int tcm = TC - 1;

    float* ws      = (float*)d_ws;
    float* state   = ws;
    float* w_buf   = state + state_f;                          // B*TC*128 f32
    unsigned short* ea16    = (unsigned short*)(w_buf + (size_t)BB * TC * MM);   // B*TC*512 us
    unsigned short* reads16 = ea16 + (size_t)BB * TC * 512;                      // B*TC*256 us
    unsigned short* qa16  = reads16 + (size_t)BB * TC * DVv;
    unsigned short* q16   = qa16 + qa16_n;
    unsigned short* wea16 = q16 + q16_n;
    unsigned short* wrd16 = wea16 + wea16_n;
    unsigned short* mk16  = wrd16 + wrd16_n;

    kcvt<<<1024, 256, 0, stream>>>(qa_tab, q_tab, W_er, W_ad, W_rd, mk,
                                   qa16, q16, wea16, wrd16, mk16,
                                   (int)qa16_n, (int)q16_n);
    for (int c = 0; c < NC; ++c) {
        int coff = c * TC;
        int rows = BB * TC;
        k1_mfma<<<rows / 128, 256, 0, stream>>>(q_data, q16, mk16, w_buf, tcs, tcm, coff);
        k2_ea_mfma<<<(rows / 128) * 4, 256, 0, stream>>>(qa_data, qa16, wea16, b_er, b_ad,
                                                         ea16, tcs, tcm, coff);
        k3_seq<<<BB, 1024, 0, stream>>>(w_buf, ea16, init_mem, state, reads16,
                                        TC, c == 0, c == NC - 1);
        k4_mfma<<<rows / 128, 256, 0, stream>>>(q_data, q16, reads16, wrd16, b_rd, W_pr, b_pr,
                                                out, tcs, tcm, coff);
    }
}